// Round 12
// baseline (400.072 us; speedup 1.0000x reference)
//
#include <hip/hip_runtime.h>
#include <hip/hip_bf16.h>
#include <stdint.h>

#define NN 8192
#define BB 256
#define EE 163840
#define HH 128
#define ZZ 256
#define LL 4
#define TPB 2           // edge tiles (of 64) per block; 1280 blocks * 2 * 64 = EE

typedef unsigned short u16;
typedef float  f32x4  __attribute__((ext_vector_type(4)));
typedef __bf16 bf16x8 __attribute__((ext_vector_type(8)));

__device__ __forceinline__ u16 f2bf(float f) {
  union { float f; uint32_t u; } v; v.f = f;
  uint32_t r = v.u + 0x7fffu + ((v.u >> 16) & 1u);   // RNE
  return (u16)(r >> 16);
}
__device__ __forceinline__ float silu_f(float x) {
  return x * __builtin_amdgcn_rcpf(1.0f + __expf(-x));
}

// ---------------------------------------------------------------------------
// Edge sorting prep: histogram -> exclusive scan -> scatter (counting sort)
// ---------------------------------------------------------------------------
__global__ void k_hist(const int* __restrict__ ei, int* __restrict__ cnt) {
  const int e = blockIdx.x * 256 + threadIdx.x;
  if (e < EE) atomicAdd(&cnt[ei[e]], 1);
}

__global__ __launch_bounds__(1024) void k_scan(const int* __restrict__ cnt,
                                               int* __restrict__ cursor) {
  __shared__ int part[1024];
  const int t = threadIdx.x;
  int v[8]; int s = 0;
#pragma unroll
  for (int j = 0; j < 8; ++j) { v[j] = s; s += cnt[t * 8 + j]; }
  part[t] = s;
  __syncthreads();
  for (int d = 1; d < 1024; d <<= 1) {
    int x = (t >= d) ? part[t - d] : 0;
    __syncthreads();
    part[t] += x;
    __syncthreads();
  }
  const int base = (t == 0) ? 0 : part[t - 1];
#pragma unroll
  for (int j = 0; j < 8; ++j) cursor[t * 8 + j] = base + v[j];
}

__global__ void k_scatter(const int* __restrict__ ei, int* __restrict__ cursor,
                          int* __restrict__ perm) {
  const int e = blockIdx.x * 256 + threadIdx.x;
  if (e < EE) {
    const int s = ei[e];
    const int ppos = atomicAdd(&cursor[s], 1);
    perm[ppos] = e;
  }
}

// ---------------------------------------------------------------------------
// Geometry precompute (layer-invariant): perm-ordered src/dst + sin-emb rows
// ---------------------------------------------------------------------------
__global__ __launch_bounds__(256) void k_geo(
    const int* __restrict__ perm, const int* __restrict__ ei,
    const float* __restrict__ fc,
    int* __restrict__ sp, int* __restrict__ dp, u16* __restrict__ egp) {
  const int i = blockIdx.x * 256 + threadIdx.x;
  if (i >= EE) return;
  const int e = perm[i];
  const int s = ei[e], d = ei[EE + e];
  sp[i] = s; dp[i] = d;
  union { u16 b[64]; uint4 u[8]; } row;
#pragma unroll
  for (int p = 0; p < 3; ++p) {
    float dd = fc[d * 3 + p] - fc[s * 3 + p];
    dd -= floorf(dd);
    float s1, c1;
    __sincosf(dd * 6.2831853071795864769f, &s1, &c1);
    row.b[p * 10]      = 0;                 // sin(0)
    row.b[30 + p * 10] = f2bf(1.0f);        // cos(0)
    float sk = s1, ck = c1;
#pragma unroll
    for (int k = 1; k < 10; ++k) {
      row.b[p * 10 + k]      = f2bf(sk);
      row.b[30 + p * 10 + k] = f2bf(ck);
      const float sn = sk * c1 + ck * s1, cn = ck * c1 - sk * s1;
      sk = sn; ck = cn;
    }
  }
#pragma unroll
  for (int j = 60; j < 64; ++j) row.b[j] = 0;
  uint4* out = (uint4*)(egp + (size_t)i * 64);
#pragma unroll
  for (int q = 0; q < 8; ++q) out[q] = row.u[q];
}

// ---------------------------------------------------------------------------
// Fused prep: weight transposes + bf16 conversions
// ---------------------------------------------------------------------------
#define R_WT1S  (LL * 128 * 128)
#define R_WT1D  (LL * 128 * 128)
#define R_WT1G  (LL * 128 * 64)
#define R_WT2   (LL * 128 * 128)
#define R_NWT1  (LL * 128 * 256)
#define R_NWT2  (LL * 128 * 128)
#define R_HWT   (128 * 384)
#define R_EMB   (100 * 128)
#define R_Z     (BB * ZZ)
#define PREP_TOT (R_WT1S + R_WT1D + R_WT1G + R_WT2 + R_NWT1 + R_NWT2 + R_HWT + R_EMB + R_Z)

__global__ __launch_bounds__(256) void k_prep(
    const float* __restrict__ ew1, const float* __restrict__ ew2,
    const float* __restrict__ nw1, const float* __restrict__ nw2,
    const float* __restrict__ Wl,  const float* __restrict__ emb,
    const float* __restrict__ z,
    u16* __restrict__ wt1s, u16* __restrict__ wt1d, u16* __restrict__ wt1g,
    u16* __restrict__ wt2,
    u16* __restrict__ nwt1, u16* __restrict__ nwt2,
    u16* __restrict__ hwt, u16* __restrict__ embbf, u16* __restrict__ zbf) {
  int idx = blockIdx.x * 256 + threadIdx.x;
  if (idx < R_WT1S) {
    const int l = idx >> 14, rem = idx & 16383;
    const int n = rem >> 7, k = rem & 127;
    wt1s[idx] = f2bf(ew1[((size_t)l * 325 + k) * 128 + n]);
    return;
  }
  idx -= R_WT1S;
  if (idx < R_WT1D) {
    const int l = idx >> 14, rem = idx & 16383;
    const int n = rem >> 7, k = rem & 127;
    wt1d[idx] = f2bf(ew1[((size_t)l * 325 + 128 + k) * 128 + n]);
    return;
  }
  idx -= R_WT1D;
  if (idx < R_WT1G) {
    const int l = idx >> 13, rem = idx & 8191;
    const int n = rem >> 6, kg = rem & 63;
    wt1g[idx] = (kg < 60) ? f2bf(ew1[((size_t)l * 325 + 256 + kg) * 128 + n]) : (u16)0;
    return;
  }
  idx -= R_WT1G;
  if (idx < R_WT2) {
    const int l = idx >> 14, rem = idx & 16383;
    const int n = rem >> 7, k = rem & 127;
    wt2[idx] = f2bf(ew2[((size_t)l * 128 + k) * 128 + n]);
    return;
  }
  idx -= R_WT2;
  if (idx < R_NWT1) {
    const int l = idx >> 15, rem = idx & 32767;
    const int n = rem >> 8, k = rem & 255;
    nwt1[idx] = f2bf(nw1[((size_t)l * 256 + k) * 128 + n]);
    return;
  }
  idx -= R_NWT1;
  if (idx < R_NWT2) {
    const int l = idx >> 14, rem = idx & 16383;
    const int n = rem >> 7, k = rem & 127;
    nwt2[idx] = f2bf(nw2[((size_t)l * 128 + k) * 128 + n]);
    return;
  }
  idx -= R_NWT2;
  if (idx < R_HWT) {
    const int n = idx / 384, k = idx % 384;
    hwt[idx] = f2bf(Wl[k * 128 + n]);
    return;
  }
  idx -= R_HWT;
  if (idx < R_EMB) { embbf[idx] = f2bf(emb[idx]); return; }
  idx -= R_EMB;
  if (idx < R_Z) { zbf[idx] = f2bf(z[idx]); }
}

// per-layer per-graph: Gl = latips @ W1_lat + b1
__global__ void k_gl(const float* __restrict__ ew1, const float* __restrict__ eb1,
                     const float* __restrict__ lat, float* __restrict__ Gl) {
  const int idx = blockIdx.x * 256 + threadIdx.x;   // L*BB*128
  if (idx >= LL * BB * 128) return;
  const int l = idx >> 15, rem = idx & 32767, g = rem >> 7, c = rem & 127;
  float s = eb1[l * 128 + c];
#pragma unroll
  for (int j = 0; j < 9; ++j) {
    const int i = j / 3, kk = j % 3;
    float lip = 0.f;
#pragma unroll
    for (int mm = 0; mm < 3; ++mm)
      lip += lat[g * 9 + i * 3 + mm] * lat[g * 9 + kk * 3 + mm];
    s += lip * ew1[((size_t)l * 325 + 316 + j) * 128 + c];
  }
  Gl[idx] = s;
}

// per-layer, per-graph conditional adapter
__global__ __launch_bounds__(128) void k_adapt(
    const float* __restrict__ cemb, const float* __restrict__ aw1,
    const float* __restrict__ ab1, const float* __restrict__ aw2,
    const float* __restrict__ ab2, const float* __restrict__ mixin,
    float* __restrict__ call) {
  __shared__ float s1[128], s2[128];
  const int l = blockIdx.x >> 8, b = blockIdx.x & 255, c = threadIdx.x;
  const float ce = cemb[b];
  s1[c] = silu_f(ce * aw1[l * 128 + c] + ab1[l * 128 + c]);
  __syncthreads();
  float a = ab2[l * 128 + c];
  for (int k = 0; k < 128; ++k) a += s1[k] * aw2[(l * 128 + k) * 128 + c];
  s2[c] = silu_f(a);
  __syncthreads();
  float o = 0.f;
  for (int k = 0; k < 128; ++k) o += s2[k] * mixin[(l * 128 + k) * 128 + c];
  call[((size_t)l * 256 + b) * 128 + c] = o;
}

// ---------------------------------------------------------------------------
// h0 via MFMA + fused layer-0 Ps/Pd
// ---------------------------------------------------------------------------
__global__ __launch_bounds__(256) void k_h0(
    const int* __restrict__ at, const int* __restrict__ n2g,
    const u16* __restrict__ embbf, const u16* __restrict__ zbf,
    const u16* __restrict__ hwt, const float* __restrict__ bl,
    const u16* __restrict__ wt1s, const u16* __restrict__ wt1d,
    const float* __restrict__ Gl,
    float* __restrict__ h, u16* __restrict__ hbf,
    float* __restrict__ Ps, float* __restrict__ Pd) {
  __shared__ __align__(16) __bf16 einp[32][392];
  __bf16 (*hs)[136] = (__bf16(*)[136])&einp[0][0];
  const int tid = threadIdx.x, lane = tid & 63, w = tid >> 6;
  const int lr = lane & 15, lk = (lane >> 4) * 8, rr = (lane >> 4) * 4;
  const int m = tid >> 3, p = tid & 7;
  const int n0 = blockIdx.x * 32;
  {
    const int n = n0 + m;
    const uint4* er = (const uint4*)(embbf + (size_t)at[n] * 128);
    *(uint4*)(&einp[m][p * 16])     = er[p * 2];
    *(uint4*)(&einp[m][p * 16 + 8]) = er[p * 2 + 1];
    const uint4* zr = (const uint4*)(zbf + (size_t)n2g[n] * 256);
#pragma unroll
    for (int q = 0; q < 4; ++q)
      *(uint4*)(&einp[m][128 + p * 32 + q * 8]) = zr[p * 4 + q];
  }
  __syncthreads();
  f32x4 acc[2][2] = {};
  {
    const u16* w0 = hwt + (size_t)(w * 32 + lr) * 384 + lk;
    const u16* w1 = hwt + (size_t)(w * 32 + 16 + lr) * 384 + lk;
#pragma unroll
    for (int kb = 0; kb < 12; ++kb) {
      bf16x8 a0 = *(const bf16x8*)(&einp[lr][kb * 32 + lk]);
      bf16x8 a1 = *(const bf16x8*)(&einp[16 + lr][kb * 32 + lk]);
      bf16x8 b0 = *(const bf16x8*)(w0 + kb * 32);
      bf16x8 b1 = *(const bf16x8*)(w1 + kb * 32);
      acc[0][0] = __builtin_amdgcn_mfma_f32_16x16x32_bf16(a0, b0, acc[0][0], 0, 0, 0);
      acc[0][1] = __builtin_amdgcn_mfma_f32_16x16x32_bf16(a0, b1, acc[0][1], 0, 0, 0);
      acc[1][0] = __builtin_amdgcn_mfma_f32_16x16x32_bf16(a1, b0, acc[1][0], 0, 0, 0);
      acc[1][1] = __builtin_amdgcn_mfma_f32_16x16x32_bf16(a1, b1, acc[1][1], 0, 0, 0);
    }
  }
  __syncthreads();   // all einp reads done; safe to overlay hs
#pragma unroll
  for (int mt = 0; mt < 2; ++mt)
#pragma unroll
    for (int nt = 0; nt < 2; ++nt) {
      const int col = w * 32 + nt * 16 + lr;
      const float bias = bl[col];
#pragma unroll
      for (int r = 0; r < 4; ++r) {
        const int row = mt * 16 + rr + r;
        const float s = acc[mt][nt][r] + bias;
        h[(size_t)(n0 + row) * 128 + col] = s;
        const u16 bf = f2bf(s);
        hbf[(size_t)(n0 + row) * 128 + col] = bf;
        hs[row][col] = *(const __bf16*)&bf;
      }
    }
  __syncthreads();   // hs ready
  f32x4 as[2][2] = {}, ad[2][2] = {};
  {
    const u16* ws0 = wt1s + (size_t)(w * 32 + lr) * 128 + lk;
    const u16* ws1 = wt1s + (size_t)(w * 32 + 16 + lr) * 128 + lk;
    const u16* wd0 = wt1d + (size_t)(w * 32 + lr) * 128 + lk;
    const u16* wd1 = wt1d + (size_t)(w * 32 + 16 + lr) * 128 + lk;
#pragma unroll
    for (int kb = 0; kb < 4; ++kb) {
      bf16x8 a0 = *(const bf16x8*)(&hs[lr][kb * 32 + lk]);
      bf16x8 a1 = *(const bf16x8*)(&hs[16 + lr][kb * 32 + lk]);
      bf16x8 bs0 = *(const bf16x8*)(ws0 + kb * 32);
      bf16x8 bs1 = *(const bf16x8*)(ws1 + kb * 32);
      bf16x8 bd0 = *(const bf16x8*)(wd0 + kb * 32);
      bf16x8 bd1 = *(const bf16x8*)(wd1 + kb * 32);
      as[0][0] = __builtin_amdgcn_mfma_f32_16x16x32_bf16(a0, bs0, as[0][0], 0, 0, 0);
      as[0][1] = __builtin_amdgcn_mfma_f32_16x16x32_bf16(a0, bs1, as[0][1], 0, 0, 0);
      as[1][0] = __builtin_amdgcn_mfma_f32_16x16x32_bf16(a1, bs0, as[1][0], 0, 0, 0);
      as[1][1] = __builtin_amdgcn_mfma_f32_16x16x32_bf16(a1, bs1, as[1][1], 0, 0, 0);
      ad[0][0] = __builtin_amdgcn_mfma_f32_16x16x32_bf16(a0, bd0, ad[0][0], 0, 0, 0);
      ad[0][1] = __builtin_amdgcn_mfma_f32_16x16x32_bf16(a0, bd1, ad[0][1], 0, 0, 0);
      ad[1][0] = __builtin_amdgcn_mfma_f32_16x16x32_bf16(a1, bd0, ad[1][0], 0, 0, 0);
      ad[1][1] = __builtin_amdgcn_mfma_f32_16x16x32_bf16(a1, bd1, ad[1][1], 0, 0, 0);
    }
  }
#pragma unroll
  for (int mt = 0; mt < 2; ++mt)
#pragma unroll
    for (int nt = 0; nt < 2; ++nt) {
      const int col = w * 32 + nt * 16 + lr;
#pragma unroll
      for (int r = 0; r < 4; ++r) {
        const int n = n0 + mt * 16 + rr + r;
        Ps[(size_t)n * 128 + col] = as[mt][nt][r] + Gl[(size_t)n2g[n] * 128 + col];
        Pd[(size_t)n * 128 + col] = ad[mt][nt][r];
      }
    }
}

// ---------------------------------------------------------------------------
// Edge MLP: T14 register-prefetched gathers + geo frags, 2 barriers/tile,
// TPB=2 (1280 blocks, 4 co-resident/CU), XCD-swizzled.
// ---------------------------------------------------------------------------
__global__ __launch_bounds__(512, 2) void k_edge(
    const float* __restrict__ Ps, const float* __restrict__ Pd,
    const int* __restrict__ sp, const int* __restrict__ dp,
    const u16* __restrict__ egp,
    const u16* __restrict__ wt1g, const u16* __restrict__ wt2,
    const float* __restrict__ eb2, float* __restrict__ agg) {
  __shared__ __align__(16) __bf16 buf0[64][136];   // t1
  __shared__ __align__(16) __bf16 buf1[64][136];   // ef

  const int tid = threadIdx.x;
  const int lane = tid & 63, w = tid >> 6;
  const int wm = w >> 2, wn = w & 3;          // 2 row-halves x 4 col-quarters
  const int lr = lane & 15, lk = (lane >> 4) * 8, rr = (lane >> 4) * 4;

  const u16* g0p  = wt1g + (size_t)(wn * 32 + lr) * 64 + lk;
  const u16* g1p  = wt1g + (size_t)(wn * 32 + 16 + lr) * 64 + lk;
  const u16* w2p0 = wt2 + (size_t)(wn * 32 + lr) * 128 + lk;
  const u16* w2p1 = wt2 + (size_t)(wn * 32 + 16 + lr) * 128 + lk;
  const float bias2_0 = eb2[wn * 32 + lr], bias2_1 = eb2[wn * 32 + 16 + lr];
  const int col0 = wn * 32 + lr, col1 = wn * 32 + 16 + lr;

  // bijective XCD swizzle: 1280 blocks = 8 XCDs x 160 contiguous blocks
  const int blk = (blockIdx.x & 7) * 160 + (blockIdx.x >> 3);
  const int tile0 = blk * TPB;

  // T14 prefetch state for the NEXT tile's Phase A inputs
  float pre[2][2][4];     // [mt][colhalf][r] = Ps[sp]+Pd[dp]
  bf16x8 ega[2][2];       // [rowhalf][kb] geo A-fragments

#define PREFETCH(gi) { \
  _Pragma("unroll") \
  for (int mt = 0; mt < 2; ++mt) \
    _Pragma("unroll") \
    for (int r = 0; r < 4; ++r) { \
      const int row = wm * 32 + mt * 16 + rr + r; \
      const float* ps = Ps + (size_t)sp[(gi) + row] * 128; \
      const float* pd = Pd + (size_t)dp[(gi) + row] * 128; \
      pre[mt][0][r] = ps[col0] + pd[col0]; \
      pre[mt][1][r] = ps[col1] + pd[col1]; \
    } \
  _Pragma("unroll") \
  for (int kb = 0; kb < 2; ++kb) { \
    ega[0][kb] = *(const bf16x8*)(egp + (size_t)((gi) + wm * 32 + lr) * 64 + kb * 32 + lk); \
    ega[1][kb] = *(const bf16x8*)(egp + (size_t)((gi) + wm * 32 + 16 + lr) * 64 + kb * 32 + lk); \
  } }

  PREFETCH(tile0 * 64);

  for (int t = 0; t < TPB; ++t) {
    const int gi0 = (tile0 + t) * 64;

    // Phase A: acc init from prefetched regs + geo GEMM (K=64); t1 -> buf0
    {
      f32x4 acc[2][2];
#pragma unroll
      for (int mt = 0; mt < 2; ++mt)
#pragma unroll
        for (int r = 0; r < 4; ++r) {
          acc[mt][0][r] = pre[mt][0][r];
          acc[mt][1][r] = pre[mt][1][r];
        }
      bf16x8 gb0[2], gb1[2];
      gb0[0] = *(const bf16x8*)(g0p);      gb0[1] = *(const bf16x8*)(g0p + 32);
      gb1[0] = *(const bf16x8*)(g1p);      gb1[1] = *(const bf16x8*)(g1p + 32);
#pragma unroll
      for (int kb = 0; kb < 2; ++kb) {
        acc[0][0] = __builtin_amdgcn_mfma_f32_16x16x32_bf16(ega[0][kb], gb0[kb], acc[0][0], 0, 0, 0);
        acc[0][1] = __builtin_amdgcn_mfma_f32_16x16x32_bf16(ega[0][kb], gb1[kb], acc[0][1], 0, 0, 0);
        acc[1][0] = __builtin_amdgcn_mfma_f32_16x16x32_bf16(ega[1][kb], gb0[kb], acc[1][0], 0, 0, 0);
        acc[1][1] = __builtin_amdgcn_mfma_f32_16x16x32_bf16(ega[1][kb], gb1[kb], acc[1][1], 0, 0, 0);
      }
#pragma unroll
      for (int mt = 0; mt < 2; ++mt)
#pragma unroll
        for (int r = 0; r < 4; ++r) {
          buf0[wm * 32 + mt * 16 + rr + r][col0] = (__bf16)silu_f(acc[mt][0][r]);
          buf0[wm * 32 + mt * 16 + rr + r][col1] = (__bf16)silu_f(acc[mt][1][r]);
        }
    }
    __syncthreads();   // bar1: buf0 ready; prior reduce (buf1 reads) done

    // Phase B: issue next tile's prefetch FIRST (overlaps GEMM2+reduce), then GEMM2
    if (t + 1 < TPB) PREFETCH(gi0 + 64);
    {
      f32x4 acc2[2][2] = {};
#pragma unroll
      for (int kb = 0; kb < 4; ++kb) {
        bf16x8 a0 = *(const bf16x8*)(&buf0[wm * 32 + lr][kb * 32 + lk]);
        bf16x8 a1 = *(const bf16x8*)(&buf0[wm * 32 + 16 + lr][kb * 32 + lk]);
        bf16x8 b0 = *(const bf16x8*)(w2p0 + kb * 32);
        bf16x8 b1 = *(const bf16x8*)(w2p1 + kb * 32);
        acc2[0][0] = __builtin_amdgcn_mfma_f32_16x16x32_bf16(a0, b0, acc2[0][0], 0, 0, 0);
        acc2[0][1] = __builtin_amdgcn_mfma_f32_16x16x32_bf16(a0, b1, acc2[0][1], 0, 0, 0);
        acc2[1][0] = __builtin_amdgcn_mfma_f32_16x16x32_bf16(a1, b0, acc2[1][0], 0, 0, 0);
        acc2[1][1] = __builtin_amdgcn_mfma_f32_16x16x32_bf16(a1, b1, acc2[1][1], 0, 0, 0);
      }
#pragma unroll
      for (int mt = 0; mt < 2; ++mt)
#pragma unroll
        for (int r = 0; r < 4; ++r) {
          buf1[wm * 32 + mt * 16 + rr + r][col0] = (__bf16)silu_f(acc2[mt][0][r] + bias2_0);
          buf1[wm * 32 + mt * 16 + rr + r][col1] = (__bf16)silu_f(acc2[mt][1][r] + bias2_1);
        }
    }
    __syncthreads();   // bar2: buf1 ready; buf0 reads done

    // Phase C: segmented reduction (4 segments of 16 rows, 128 cols)
    {
      const int col = tid & 127, seg = tid >> 7, r0 = seg * 16;
      int curS = sp[gi0 + r0];
      float a = 0.f;
#pragma unroll 4
      for (int r = 0; r < 16; ++r) {
        const int s = sp[gi0 + r0 + r];
        if (s != curS) {
          unsafeAtomicAdd(&agg[(size_t)curS * HH + col], a);
          curS = s; a = 0.f;
        }
        a += (float)buf1[r0 + r][col];
      }
      unsafeAtomicAdd(&agg[(size_t)curS * HH + col], a);
    }
    // no barrier: next Phase A writes buf0 only; bar1 fences buf1 reuse
  }
#undef PREFETCH
}

// ---------------------------------------------------------------------------
// Node MLP via MFMA (8 waves, 16 cols/wave) + fused next-layer Ps/Pd
// ---------------------------------------------------------------------------
__global__ __launch_bounds__(512) void k_node(
    float* __restrict__ h, float* __restrict__ agg, const int* __restrict__ cnt,
    const u16* __restrict__ nwt1, const float* __restrict__ nb1,
    const u16* __restrict__ nwt2, const float* __restrict__ nb2,
    const float* __restrict__ cl, const int* __restrict__ n2g,
    u16* __restrict__ hbf,
    const u16* __restrict__ wt1s, const u16* __restrict__ wt1d,
    const float* __restrict__ Gl,
    float* __restrict__ Ps, float* __restrict__ Pd) {
  __shared__ __align__(16) __bf16 einp[32][264];
  __shared__ __align__(16) __bf16 t1n[32][136];
  const int tid = threadIdx.x, lane = tid & 63, w = tid >> 6;   // 8 waves
  const int lr = lane & 15, lk = (lane >> 4) * 8, rr = (lane >> 4) * 4;
  const int m = tid >> 4, p = tid & 15;    // staging: 16 threads per node
  const int n0 = blockIdx.x * 32;
  const int col = w * 16 + lr;             // each wave owns 16 cols
  {
    const int n = n0 + m;
    const uint4* hr = (const uint4*)(hbf + (size_t)n * 128);
    *(uint4*)(&einp[m][p * 8]) = hr[p];
    const float inv = 1.f / fmaxf((float)cnt[n], 1.f);
    const float4* ar = (const float4*)(agg + (size_t)n * 128);
    union { __bf16 b[8]; uint4 u; } tmp;
#pragma unroll
    for (int q = 0; q < 2; ++q) {
      const float4 v = ar[p * 2 + q];
      tmp.b[q * 4 + 0] = (__bf16)(v.x * inv);
      tmp.b[q * 4 + 1] = (__bf16)(v.y * inv);
      tmp.b[q * 4 + 2] = (__bf16)(v.z * inv);
      tmp.b[q * 4 + 3] = (__bf16)(v.w * inv);
    }
    *(uint4*)(&einp[m][128 + p * 8]) = tmp.u;
  }
  __syncthreads();
  f32x4 acc[2] = {};
  {
    const u16* w0 = nwt1 + (size_t)col * 256 + lk;
#pragma unroll
    for (int kb = 0; kb < 8; ++kb) {
      bf16x8 a0 = *(const bf16x8*)(&einp[lr][kb * 32 + lk]);
      bf16x8 a1 = *(const bf16x8*)(&einp[16 + lr][kb * 32 + lk]);
      bf16x8 b0 = *(const bf16x8*)(w0 + kb * 32);
      acc[0] = __builtin_amdgcn_mfma_f32_16x16x32_bf16(a0, b0, acc[0], 0, 0, 0);
      acc[1] = __builtin_amdgcn_mfma_f32_16x16x32_bf16(a1, b0, acc[1], 0, 0, 0);
    }
  }
  {
    const float bias = nb1[col];
#pragma unroll
    for (int mt = 0; mt < 2; ++mt)
#pragma unroll
      for (int r = 0; r < 4; ++r)
        t1n[mt * 16 + rr + r][col] = (__bf16)silu_f(acc[mt][r] + bias);
  }
  __syncthreads();
  f32x4 acc2[2] = {};
  {
    const u16* w0 = nwt2 + (size_t)col * 128 + lk;
#pragma unroll
    for (int kb = 0; kb < 4; ++kb) {
      bf16x8 a0 = *(const bf16x8*)(&t1n[lr][kb * 32 + lk]);
      bf16x8 a1 = *(const bf16x8*)(&t1n[16 + lr][kb * 32 + lk]);
      bf16x8 b0 = *(const bf16x8*)(w0 + kb * 32);
      acc2[0] = __builtin_amdgcn_mfma_f32_16x16x32_bf16(a0, b0, acc2[0], 0, 0, 0);
      acc2[1] = __builtin_amdgcn_mfma_f32_16x16x32_bf16(a1, b0, acc2[1], 0, 0, 0);
    }
  }
  __syncthreads();   // t1n reads done; safe to overwrite with new hbf
  {
    const float bias = nb2[col];
#pragma unroll
    for (int mt = 0; mt < 2; ++mt)
#pragma unroll
      for (int r = 0; r < 4; ++r) {
        const int row = mt * 16 + rr + r;
        const int n = n0 + row;
        const float rv = h[(size_t)n * 128 + col] + silu_f(acc2[mt][r] + bias)
                       + cl[(size_t)n2g[n] * 128 + col];
        h[(size_t)n * 128 + col] = rv;
        const u16 bf = f2bf(rv);
        hbf[(size_t)n * 128 + col] = bf;
        t1n[row][col] = *(const __bf16*)&bf;
        agg[(size_t)n * 128 + col] = 0.f;
      }
  }
  if (!wt1s) return;
  __syncthreads();   // new hbf in t1n ready
  f32x4 as[2] = {}, ad[2] = {};
  {
    const u16* ws0 = wt1s + (size_t)col * 128 + lk;
    const u16* wd0 = wt1d + (size_t)col * 128 + lk;
#pragma unroll
    for (int kb = 0; kb < 4; ++kb) {
      bf16x8 a0 = *(const bf16x8*)(&t1n[lr][kb * 32 + lk]);
      bf16x8 a1 = *(const bf16x8*)(&t1n[16 + lr][kb * 32 + lk]);
      bf16x8 bs0 = *(const bf16x8*)(ws0 + kb * 32);
      bf16x8 bd0 = *(const bf16x8*)(wd0 + kb * 32);
      as[0] = __builtin_amdgcn_mfma_f32_16x16x32_bf16(a0, bs0, as[0], 0, 0, 0);
      as[1] = __builtin_amdgcn_mfma_f32_16x16x32_bf16(a1, bs0, as[1], 0, 0, 0);
      ad[0] = __builtin_amdgcn_mfma_f32_16x16x32_bf16(a0, bd0, ad[0], 0, 0, 0);
      ad[1] = __builtin_amdgcn_mfma_f32_16x16x32_bf16(a1, bd0, ad[1], 0, 0, 0);
    }
  }
#pragma unroll
  for (int mt = 0; mt < 2; ++mt)
#pragma unroll
    for (int r = 0; r < 4; ++r) {
      const int n = n0 + mt * 16 + rr + r;
      Ps[(size_t)n * 128 + col] = as[mt][r] + Gl[(size_t)n2g[n] * 128 + col];
      Pd[(size_t)n * 128 + col] = ad[mt][r];
    }
}

// ---------------------------------------------------------------------------
// Output heads (coord + lattice fused)
// ---------------------------------------------------------------------------
__global__ __launch_bounds__(256) void k_heads(
    const float* __restrict__ h, const float* __restrict__ Wc,
    const float* __restrict__ Wl9, const float* __restrict__ lat,
    float* __restrict__ out) {
  const int b = blockIdx.x, tid = threadIdx.x;
  if (b < NN * 3 / 256) {
    const int idx = b * 256 + tid;
    const int n = idx / 3, j = idx % 3;
    float s = 0.f;
    for (int k = 0; k < 128; ++k) s += h[n * 128 + k] * Wc[k * 3 + j];
    out[BB * 9 + idx] = s;
    return;
  }
  const int g = b - NN * 3 / 256;
  __shared__ float part[2][128];
  __shared__ float gf[128];
  __shared__ float lo[9];
  const int c = tid & 127, half = tid >> 7;
  float s = 0.f;
  for (int mm = 0; mm < 16; ++mm)
    s += h[((size_t)g * 32 + half * 16 + mm) * 128 + c];
  part[half][c] = s;
  __syncthreads();
  if (tid < 128) gf[tid] = (part[0][tid] + part[1][tid]) * (1.f / 32.f);
  __syncthreads();
  if (tid < 9) {
    float t = 0.f;
    for (int k = 0; k < 128; ++k) t += gf[k] * Wl9[k * 9 + tid];
    lo[tid] = t;
  }
  __syncthreads();
  if (tid < 9) {
    const int i = tid / 3, kk = tid % 3;
    float t = 0.f;
#pragma unroll
    for (int j = 0; j < 3; ++j) t += lo[i * 3 + j] * lat[g * 9 + j * 3 + kk];
    out[g * 9 + tid] = t;
  }
}

// ---------------------------------------------------------------------------
extern "C" void kernel_launch(void* const* d_in, const int* in_sizes, int n_in,
                              void* d_out, int out_size, void* d_ws, size_t ws_size,
                              hipStream_t stream) {
  const int*   atom_types = (const int*)  d_in[0];
  const float* frac       = (const float*)d_in[1];
  const float* lattices   = (const float*)d_in[2];
  const float* z          = (const float*)d_in[3];
  const float* cemb       = (const float*)d_in[4];
  const int*   ei         = (const int*)  d_in[5];
  const int*   n2g        = (const int*)  d_in[6];
  const float* emb        = (const float*)d_in[7];
  const float* W_lat      = (const float*)d_in[8];
  const float* b_lat      = (const float*)d_in[9];
  const float* ew1        = (const float*)d_in[10];
  const float* eb1        = (const float*)d_in[11];
  const float* ew2        = (const float*)d_in[12];
  const float* eb2        = (const float*)d_in[13];
  const float* nw1        = (const float*)d_in[14];
  const float* nb1        = (const float*)d_in[15];
  const float* nw2        = (const float*)d_in[16];
  const float* nb2        = (const float*)d_in[17];
  const float* mixin      = (const float*)d_in[18];
  const float* aw1        = (const float*)d_in[19];
  const float* ab1        = (const float*)d_in[20];
  const float* aw2        = (const float*)d_in[21];
  const float* ab2        = (const float*)d_in[22];
  const float* Wc         = (const float*)d_in[23];
  const float* Wl9        = (const float*)d_in[24];
  float* out = (float*)d_out;

  uint8_t* base = (uint8_t*)d_ws;
  size_t off = 0;
  auto carve = [&](size_t bytes) -> void* {
    void* r = base + off;
    off = (off + bytes + 255) & ~(size_t)255;
    return r;
  };
  float* h      = (float*)carve((size_t)NN * HH * 4);
  u16*   hbf    = (u16*)  carve((size_t)NN * HH * 2);
  float* agg    = (float*)carve((size_t)NN * HH * 4);
  float* Ps     = (float*)carve((size_t)NN * HH * 4);
  float* Pd     = (float*)carve((size_t)NN * HH * 4);
  float* Gl     = (float*)carve((size_t)LL * BB * HH * 4);
  int*   cnt    = (int*)  carve((size_t)NN * 4);
  int*   cursor = (int*)  carve((size_t)NN * 4);
  int*   perm   = (int*)  carve((size_t)EE * 4);
  int*   sp     = (int*)  carve((size_t)EE * 4);
  int*   dp     = (int*)  carve((size_t)EE * 4);
  u16*   egp    = (u16*)  carve((size_t)EE * 64 * 2);
  float* call   = (float*)carve((size_t)LL * BB * HH * 4);
  u16*   wt1s   = (u16*)  carve((size_t)R_WT1S * 2);
  u16*   wt1d   = (u16*)  carve((size_t)R_WT1D * 2);
  u16*   wt1g   = (u16*)  carve((size_t)R_WT1G * 2);
  u16*   wt2    = (u16*)  carve((size_t)R_WT2 * 2);
  u16*   nwt1   = (u16*)  carve((size_t)R_NWT1 * 2);
  u16*   nwt2   = (u16*)  carve((size_t)R_NWT2 * 2);
  u16*   hwt    = (u16*)  carve((size_t)R_HWT * 2);
  u16*   embbf  = (u16*)  carve((size_t)R_EMB * 2);
  u16*   zbf    = (u16*)  carve((size_t)R_Z * 2);

  hipMemsetAsync(cnt, 0, (size_t)NN * 4, stream);
  k_hist<<<EE / 256, 256, 0, stream>>>(ei, cnt);
  k_scan<<<1, 1024, 0, stream>>>(cnt, cursor);
  k_scatter<<<EE / 256, 256, 0, stream>>>(ei, cursor, perm);
  k_geo<<<EE / 256, 256, 0, stream>>>(perm, ei, frac, sp, dp, egp);
  k_prep<<<(PREP_TOT + 255) / 256, 256, 0, stream>>>(
      ew1, ew2, nw1, nw2, W_lat, emb, z,
      wt1s, wt1d, wt1g, wt2, nwt1, nwt2, hwt, embbf, zbf);
  k_gl<<<(LL * BB * 128 + 255) / 256, 256, 0, stream>>>(ew1, eb1, lattices, Gl);
  k_adapt<<<LL * BB, 128, 0, stream>>>(cemb, aw1, ab1, aw2, ab2, mixin, call);
  k_h0<<<NN / 32, 256, 0, stream>>>(atom_types, n2g, embbf, zbf, hwt, b_lat,
                                    wt1s, wt1d, Gl, h, hbf, Ps, Pd);
  hipMemsetAsync(agg, 0, (size_t)NN * HH * 4, stream);  // layers 1..3 zeroed by k_node

  for (int l = 0; l < LL; ++l) {
    k_edge<<<EE / (64 * TPB), 512, 0, stream>>>(Ps, Pd, sp, dp, egp,
        wt1g + (size_t)l * 128 * 64, wt2 + (size_t)l * 128 * 128,
        eb2 + l * 128, agg);
    const bool more = (l + 1 < LL);
    k_node<<<NN / 32, 512, 0, stream>>>(h, agg, cnt,
        nwt1 + (size_t)l * 128 * 256, nb1 + l * 128,
        nwt2 + (size_t)l * 128 * 128, nb2 + l * 128,
        call + (size_t)l * BB * HH, n2g, hbf,
        more ? wt1s + (size_t)(l + 1) * 128 * 128 : (const u16*)nullptr,
        more ? wt1d + (size_t)(l + 1) * 128 * 128 : (const u16*)nullptr,
        more ? Gl + (size_t)(l + 1) * BB * HH : (const float*)nullptr,
        Ps, Pd);
  }

  k_heads<<<NN * 3 / 256 + BB, 256, 0, stream>>>(h, Wc, Wl9, lattices, out);
}

// Round 13
// 305.067 us; speedup vs baseline: 1.3114x; 1.3114x over previous
//
#include <hip/hip_runtime.h>
#include <hip/hip_bf16.h>
#include <stdint.h>

#define NN 8192
#define BB 256
#define EE 163840
#define HH 128
#define ZZ 256
#define LL 4
#define TPB 5           // edge tiles (of 64) per block; 512 blocks * 5 * 64 = EE

typedef unsigned short u16;
typedef float  f32x4  __attribute__((ext_vector_type(4)));
typedef __bf16 bf16x8 __attribute__((ext_vector_type(8)));

__device__ __forceinline__ u16 f2bf(float f) {
  union { float f; uint32_t u; } v; v.f = f;
  uint32_t r = v.u + 0x7fffu + ((v.u >> 16) & 1u);   // RNE
  return (u16)(r >> 16);
}
__device__ __forceinline__ float silu_f(float x) {
  return x * __builtin_amdgcn_rcpf(1.0f + __expf(-x));
}

// ---------------------------------------------------------------------------
// Edge sorting prep: histogram -> exclusive scan -> scatter (counting sort)
// ---------------------------------------------------------------------------
__global__ void k_hist(const int* __restrict__ ei, int* __restrict__ cnt) {
  const int e = blockIdx.x * 256 + threadIdx.x;
  if (e < EE) atomicAdd(&cnt[ei[e]], 1);
}

__global__ __launch_bounds__(1024) void k_scan(const int* __restrict__ cnt,
                                               int* __restrict__ cursor) {
  __shared__ int part[1024];
  const int t = threadIdx.x;
  int v[8]; int s = 0;
#pragma unroll
  for (int j = 0; j < 8; ++j) { v[j] = s; s += cnt[t * 8 + j]; }
  part[t] = s;
  __syncthreads();
  for (int d = 1; d < 1024; d <<= 1) {
    int x = (t >= d) ? part[t - d] : 0;
    __syncthreads();
    part[t] += x;
    __syncthreads();
  }
  const int base = (t == 0) ? 0 : part[t - 1];
#pragma unroll
  for (int j = 0; j < 8; ++j) cursor[t * 8 + j] = base + v[j];
}

__global__ void k_scatter(const int* __restrict__ ei, int* __restrict__ cursor,
                          int* __restrict__ perm) {
  const int e = blockIdx.x * 256 + threadIdx.x;
  if (e < EE) {
    const int s = ei[e];
    const int ppos = atomicAdd(&cursor[s], 1);
    perm[ppos] = e;
  }
}

// perm-ordered src/dst (layer-invariant)
__global__ void k_geo(const int* __restrict__ perm, const int* __restrict__ ei,
                      int* __restrict__ sp, int* __restrict__ dp) {
  const int i = blockIdx.x * 256 + threadIdx.x;
  if (i >= EE) return;
  const int e = perm[i];
  sp[i] = ei[e];
  dp[i] = ei[EE + e];
}

// ---------------------------------------------------------------------------
// Fused prep: weight transposes + bf16 conversions
// ---------------------------------------------------------------------------
#define R_WT1S  (LL * 128 * 128)
#define R_WT1D  (LL * 128 * 128)
#define R_WT1G  (LL * 128 * 64)
#define R_WT2   (LL * 128 * 128)
#define R_NWT1  (LL * 128 * 256)
#define R_NWT2  (LL * 128 * 128)
#define R_HWT   (128 * 384)
#define R_EMB   (100 * 128)
#define R_Z     (BB * ZZ)
#define PREP_TOT (R_WT1S + R_WT1D + R_WT1G + R_WT2 + R_NWT1 + R_NWT2 + R_HWT + R_EMB + R_Z)

__global__ __launch_bounds__(256) void k_prep(
    const float* __restrict__ ew1, const float* __restrict__ ew2,
    const float* __restrict__ nw1, const float* __restrict__ nw2,
    const float* __restrict__ Wl,  const float* __restrict__ emb,
    const float* __restrict__ z,
    u16* __restrict__ wt1s, u16* __restrict__ wt1d, u16* __restrict__ wt1g,
    u16* __restrict__ wt2,
    u16* __restrict__ nwt1, u16* __restrict__ nwt2,
    u16* __restrict__ hwt, u16* __restrict__ embbf, u16* __restrict__ zbf) {
  int idx = blockIdx.x * 256 + threadIdx.x;
  if (idx < R_WT1S) {
    const int l = idx >> 14, rem = idx & 16383;
    const int n = rem >> 7, k = rem & 127;
    wt1s[idx] = f2bf(ew1[((size_t)l * 325 + k) * 128 + n]);
    return;
  }
  idx -= R_WT1S;
  if (idx < R_WT1D) {
    const int l = idx >> 14, rem = idx & 16383;
    const int n = rem >> 7, k = rem & 127;
    wt1d[idx] = f2bf(ew1[((size_t)l * 325 + 128 + k) * 128 + n]);
    return;
  }
  idx -= R_WT1D;
  if (idx < R_WT1G) {
    const int l = idx >> 13, rem = idx & 8191;
    const int n = rem >> 6, kg = rem & 63;
    wt1g[idx] = (kg < 60) ? f2bf(ew1[((size_t)l * 325 + 256 + kg) * 128 + n]) : (u16)0;
    return;
  }
  idx -= R_WT1G;
  if (idx < R_WT2) {
    const int l = idx >> 14, rem = idx & 16383;
    const int n = rem >> 7, k = rem & 127;
    wt2[idx] = f2bf(ew2[((size_t)l * 128 + k) * 128 + n]);
    return;
  }
  idx -= R_WT2;
  if (idx < R_NWT1) {
    const int l = idx >> 15, rem = idx & 32767;
    const int n = rem >> 8, k = rem & 255;
    nwt1[idx] = f2bf(nw1[((size_t)l * 256 + k) * 128 + n]);
    return;
  }
  idx -= R_NWT1;
  if (idx < R_NWT2) {
    const int l = idx >> 14, rem = idx & 16383;
    const int n = rem >> 7, k = rem & 127;
    nwt2[idx] = f2bf(nw2[((size_t)l * 128 + k) * 128 + n]);
    return;
  }
  idx -= R_NWT2;
  if (idx < R_HWT) {
    const int n = idx / 384, k = idx % 384;
    hwt[idx] = f2bf(Wl[k * 128 + n]);
    return;
  }
  idx -= R_HWT;
  if (idx < R_EMB) { embbf[idx] = f2bf(emb[idx]); return; }
  idx -= R_EMB;
  if (idx < R_Z) { zbf[idx] = f2bf(z[idx]); }
}

// per-layer per-graph: Gl = latips @ W1_lat + b1
__global__ void k_gl(const float* __restrict__ ew1, const float* __restrict__ eb1,
                     const float* __restrict__ lat, float* __restrict__ Gl) {
  const int idx = blockIdx.x * 256 + threadIdx.x;   // L*BB*128
  if (idx >= LL * BB * 128) return;
  const int l = idx >> 15, rem = idx & 32767, g = rem >> 7, c = rem & 127;
  float s = eb1[l * 128 + c];
#pragma unroll
  for (int j = 0; j < 9; ++j) {
    const int i = j / 3, kk = j % 3;
    float lip = 0.f;
#pragma unroll
    for (int mm = 0; mm < 3; ++mm)
      lip += lat[g * 9 + i * 3 + mm] * lat[g * 9 + kk * 3 + mm];
    s += lip * ew1[((size_t)l * 325 + 316 + j) * 128 + c];
  }
  Gl[idx] = s;
}

// per-layer, per-graph conditional adapter
__global__ __launch_bounds__(128) void k_adapt(
    const float* __restrict__ cemb, const float* __restrict__ aw1,
    const float* __restrict__ ab1, const float* __restrict__ aw2,
    const float* __restrict__ ab2, const float* __restrict__ mixin,
    float* __restrict__ call) {
  __shared__ float s1[128], s2[128];
  const int l = blockIdx.x >> 8, b = blockIdx.x & 255, c = threadIdx.x;
  const float ce = cemb[b];
  s1[c] = silu_f(ce * aw1[l * 128 + c] + ab1[l * 128 + c]);
  __syncthreads();
  float a = ab2[l * 128 + c];
  for (int k = 0; k < 128; ++k) a += s1[k] * aw2[(l * 128 + k) * 128 + c];
  s2[c] = silu_f(a);
  __syncthreads();
  float o = 0.f;
  for (int k = 0; k < 128; ++k) o += s2[k] * mixin[(l * 128 + k) * 128 + c];
  call[((size_t)l * 256 + b) * 128 + c] = o;
}

// ---------------------------------------------------------------------------
// h0 via MFMA + fused layer-0 Ps/Pd
// ---------------------------------------------------------------------------
__global__ __launch_bounds__(256) void k_h0(
    const int* __restrict__ at, const int* __restrict__ n2g,
    const u16* __restrict__ embbf, const u16* __restrict__ zbf,
    const u16* __restrict__ hwt, const float* __restrict__ bl,
    const u16* __restrict__ wt1s, const u16* __restrict__ wt1d,
    const float* __restrict__ Gl,
    float* __restrict__ h, u16* __restrict__ hbf,
    float* __restrict__ Ps, float* __restrict__ Pd) {
  __shared__ __align__(16) __bf16 einp[32][392];
  __bf16 (*hs)[136] = (__bf16(*)[136])&einp[0][0];
  const int tid = threadIdx.x, lane = tid & 63, w = tid >> 6;
  const int lr = lane & 15, lk = (lane >> 4) * 8, rr = (lane >> 4) * 4;
  const int m = tid >> 3, p = tid & 7;
  const int n0 = blockIdx.x * 32;
  {
    const int n = n0 + m;
    const uint4* er = (const uint4*)(embbf + (size_t)at[n] * 128);
    *(uint4*)(&einp[m][p * 16])     = er[p * 2];
    *(uint4*)(&einp[m][p * 16 + 8]) = er[p * 2 + 1];
    const uint4* zr = (const uint4*)(zbf + (size_t)n2g[n] * 256);
#pragma unroll
    for (int q = 0; q < 4; ++q)
      *(uint4*)(&einp[m][128 + p * 32 + q * 8]) = zr[p * 4 + q];
  }
  __syncthreads();
  f32x4 acc[2][2] = {};
  {
    const u16* w0 = hwt + (size_t)(w * 32 + lr) * 384 + lk;
    const u16* w1 = hwt + (size_t)(w * 32 + 16 + lr) * 384 + lk;
#pragma unroll
    for (int kb = 0; kb < 12; ++kb) {
      bf16x8 a0 = *(const bf16x8*)(&einp[lr][kb * 32 + lk]);
      bf16x8 a1 = *(const bf16x8*)(&einp[16 + lr][kb * 32 + lk]);
      bf16x8 b0 = *(const bf16x8*)(w0 + kb * 32);
      bf16x8 b1 = *(const bf16x8*)(w1 + kb * 32);
      acc[0][0] = __builtin_amdgcn_mfma_f32_16x16x32_bf16(a0, b0, acc[0][0], 0, 0, 0);
      acc[0][1] = __builtin_amdgcn_mfma_f32_16x16x32_bf16(a0, b1, acc[0][1], 0, 0, 0);
      acc[1][0] = __builtin_amdgcn_mfma_f32_16x16x32_bf16(a1, b0, acc[1][0], 0, 0, 0);
      acc[1][1] = __builtin_amdgcn_mfma_f32_16x16x32_bf16(a1, b1, acc[1][1], 0, 0, 0);
    }
  }
  __syncthreads();   // all einp reads done; safe to overlay hs
#pragma unroll
  for (int mt = 0; mt < 2; ++mt)
#pragma unroll
    for (int nt = 0; nt < 2; ++nt) {
      const int col = w * 32 + nt * 16 + lr;
      const float bias = bl[col];
#pragma unroll
      for (int r = 0; r < 4; ++r) {
        const int row = mt * 16 + rr + r;
        const float s = acc[mt][nt][r] + bias;
        h[(size_t)(n0 + row) * 128 + col] = s;
        const u16 bf = f2bf(s);
        hbf[(size_t)(n0 + row) * 128 + col] = bf;
        hs[row][col] = *(const __bf16*)&bf;
      }
    }
  __syncthreads();   // hs ready
  f32x4 as[2][2] = {}, ad[2][2] = {};
  {
    const u16* ws0 = wt1s + (size_t)(w * 32 + lr) * 128 + lk;
    const u16* ws1 = wt1s + (size_t)(w * 32 + 16 + lr) * 128 + lk;
    const u16* wd0 = wt1d + (size_t)(w * 32 + lr) * 128 + lk;
    const u16* wd1 = wt1d + (size_t)(w * 32 + 16 + lr) * 128 + lk;
#pragma unroll
    for (int kb = 0; kb < 4; ++kb) {
      bf16x8 a0 = *(const bf16x8*)(&hs[lr][kb * 32 + lk]);
      bf16x8 a1 = *(const bf16x8*)(&hs[16 + lr][kb * 32 + lk]);
      bf16x8 bs0 = *(const bf16x8*)(ws0 + kb * 32);
      bf16x8 bs1 = *(const bf16x8*)(ws1 + kb * 32);
      bf16x8 bd0 = *(const bf16x8*)(wd0 + kb * 32);
      bf16x8 bd1 = *(const bf16x8*)(wd1 + kb * 32);
      as[0][0] = __builtin_amdgcn_mfma_f32_16x16x32_bf16(a0, bs0, as[0][0], 0, 0, 0);
      as[0][1] = __builtin_amdgcn_mfma_f32_16x16x32_bf16(a0, bs1, as[0][1], 0, 0, 0);
      as[1][0] = __builtin_amdgcn_mfma_f32_16x16x32_bf16(a1, bs0, as[1][0], 0, 0, 0);
      as[1][1] = __builtin_amdgcn_mfma_f32_16x16x32_bf16(a1, bs1, as[1][1], 0, 0, 0);
      ad[0][0] = __builtin_amdgcn_mfma_f32_16x16x32_bf16(a0, bd0, ad[0][0], 0, 0, 0);
      ad[0][1] = __builtin_amdgcn_mfma_f32_16x16x32_bf16(a0, bd1, ad[0][1], 0, 0, 0);
      ad[1][0] = __builtin_amdgcn_mfma_f32_16x16x32_bf16(a1, bd0, ad[1][0], 0, 0, 0);
      ad[1][1] = __builtin_amdgcn_mfma_f32_16x16x32_bf16(a1, bd1, ad[1][1], 0, 0, 0);
    }
  }
#pragma unroll
  for (int mt = 0; mt < 2; ++mt)
#pragma unroll
    for (int nt = 0; nt < 2; ++nt) {
      const int col = w * 32 + nt * 16 + lr;
#pragma unroll
      for (int r = 0; r < 4; ++r) {
        const int n = n0 + mt * 16 + rr + r;
        Ps[(size_t)n * 128 + col] = as[mt][nt][r] + Gl[(size_t)n2g[n] * 128 + col];
        Pd[(size_t)n * 128 + col] = ad[mt][nt][r];
      }
    }
}

// ---------------------------------------------------------------------------
// Edge MLP: R8 structure (in-kernel sin-emb staged to LDS, TPB=5, 3 barriers)
// + T14 prefetch of Ps/Pd gathers issued at top of Phase B.
// ---------------------------------------------------------------------------
__global__ __launch_bounds__(512, 2) void k_edge(
    const float* __restrict__ Ps, const float* __restrict__ Pd,
    const float* __restrict__ fc,
    const int* __restrict__ sp, const int* __restrict__ dp,
    const u16* __restrict__ wt1g, const u16* __restrict__ wt2,
    const float* __restrict__ eb2, float* __restrict__ agg) {
  __shared__ __align__(16) __bf16 eg[64][72];      // sin-emb K=64 (single buffer)
  __shared__ __align__(16) __bf16 buf0[64][136];   // t1
  __shared__ __align__(16) __bf16 buf1[64][136];   // ef

  const int tid = threadIdx.x;
  const int lane = tid & 63, w = tid >> 6;
  const int wm = w >> 2, wn = w & 3;          // 2 row-halves x 4 col-quarters
  const int lr = lane & 15, lk = (lane >> 4) * 8, rr = (lane >> 4) * 4;
  const int m = tid >> 3, p = tid & 7;        // staging: 8 threads per edge

  const u16* g0p  = wt1g + (size_t)(wn * 32 + lr) * 64 + lk;
  const u16* g1p  = wt1g + (size_t)(wn * 32 + 16 + lr) * 64 + lk;
  const u16* w2p0 = wt2 + (size_t)(wn * 32 + lr) * 128 + lk;
  const u16* w2p1 = wt2 + (size_t)(wn * 32 + 16 + lr) * 128 + lk;
  const float bias2_0 = eb2[wn * 32 + lr], bias2_1 = eb2[wn * 32 + 16 + lr];
  const int col0 = wn * 32 + lr, col1 = wn * 32 + 16 + lr;

  const int tile0 = blockIdx.x * TPB;

  // T14 prefetch state: Ps[sp]+Pd[dp] for the upcoming tile's Phase A
  float pre[2][2][4];
#define PREFETCH(gi) { \
  _Pragma("unroll") \
  for (int mt = 0; mt < 2; ++mt) \
    _Pragma("unroll") \
    for (int r = 0; r < 4; ++r) { \
      const int row = wm * 32 + mt * 16 + rr + r; \
      const float* ps = Ps + (size_t)sp[(gi) + row] * 128; \
      const float* pd = Pd + (size_t)dp[(gi) + row] * 128; \
      pre[mt][0][r] = ps[col0] + pd[col0]; \
      pre[mt][1][r] = ps[col1] + pd[col1]; \
    } }

  // stage sin-emb for tile at gi into eg (3 of 8 threads per edge active)
#define STAGE_EG(gi) { \
  if (p < 3) { \
    const int s = sp[(gi) + m], d = dp[(gi) + m]; \
    float dd = fc[d * 3 + p] - fc[s * 3 + p]; \
    dd -= floorf(dd); \
    float s1, c1; \
    __sincosf(dd * 6.2831853071795864769f, &s1, &c1); \
    eg[m][p * 10]      = (__bf16)0.0f; \
    eg[m][30 + p * 10] = (__bf16)1.0f; \
    float sk = s1, ck = c1; \
    _Pragma("unroll") \
    for (int k = 1; k < 10; ++k) { \
      eg[m][p * 10 + k]      = (__bf16)sk; \
      eg[m][30 + p * 10 + k] = (__bf16)ck; \
      const float sn = sk * c1 + ck * s1, cn = ck * c1 - sk * s1; \
      sk = sn; ck = cn; \
    } \
  } }

  // prologue: zero eg pad, stage tile0 eg, prefetch tile0 gathers
  for (int i = tid; i < 64 * 12; i += 512) eg[i / 12][60 + i % 12] = (__bf16)0.0f;
  STAGE_EG(tile0 * 64);
  PREFETCH(tile0 * 64);
  __syncthreads();

  for (int t = 0; t < TPB; ++t) {
    const int gi0 = (tile0 + t) * 64;

    // Phase A: acc init from prefetched regs + geo GEMM (eg LDS); t1 -> buf0
    {
      f32x4 acc[2][2];
#pragma unroll
      for (int mt = 0; mt < 2; ++mt)
#pragma unroll
        for (int r = 0; r < 4; ++r) {
          acc[mt][0][r] = pre[mt][0][r];
          acc[mt][1][r] = pre[mt][1][r];
        }
      bf16x8 gb0[2], gb1[2];
      gb0[0] = *(const bf16x8*)(g0p);      gb0[1] = *(const bf16x8*)(g0p + 32);
      gb1[0] = *(const bf16x8*)(g1p);      gb1[1] = *(const bf16x8*)(g1p + 32);
#pragma unroll
      for (int kb = 0; kb < 2; ++kb) {
        bf16x8 a0 = *(const bf16x8*)(&eg[wm * 32 + lr][kb * 32 + lk]);
        bf16x8 a1 = *(const bf16x8*)(&eg[wm * 32 + 16 + lr][kb * 32 + lk]);
        acc[0][0] = __builtin_amdgcn_mfma_f32_16x16x32_bf16(a0, gb0[kb], acc[0][0], 0, 0, 0);
        acc[0][1] = __builtin_amdgcn_mfma_f32_16x16x32_bf16(a0, gb1[kb], acc[0][1], 0, 0, 0);
        acc[1][0] = __builtin_amdgcn_mfma_f32_16x16x32_bf16(a1, gb0[kb], acc[1][0], 0, 0, 0);
        acc[1][1] = __builtin_amdgcn_mfma_f32_16x16x32_bf16(a1, gb1[kb], acc[1][1], 0, 0, 0);
      }
#pragma unroll
      for (int mt = 0; mt < 2; ++mt)
#pragma unroll
        for (int r = 0; r < 4; ++r) {
          buf0[wm * 32 + mt * 16 + rr + r][col0] = (__bf16)silu_f(acc[mt][0][r]);
          buf0[wm * 32 + mt * 16 + rr + r][col1] = (__bf16)silu_f(acc[mt][1][r]);
        }
    }
    __syncthreads();   // bar1: buf0 ready; eg(t) reads + buf1 reads (prev D) done

    // Phase B: prefetch next gathers, stage next eg, GEMM2 -> regs
    const bool has_next = (t + 1 < TPB);
    if (has_next) {
      PREFETCH(gi0 + 64);
      STAGE_EG(gi0 + 64);
    }
    f32x4 acc2[2][2] = {};
#pragma unroll
    for (int kb = 0; kb < 4; ++kb) {
      bf16x8 a0 = *(const bf16x8*)(&buf0[wm * 32 + lr][kb * 32 + lk]);
      bf16x8 a1 = *(const bf16x8*)(&buf0[wm * 32 + 16 + lr][kb * 32 + lk]);
      bf16x8 b0 = *(const bf16x8*)(w2p0 + kb * 32);
      bf16x8 b1 = *(const bf16x8*)(w2p1 + kb * 32);
      acc2[0][0] = __builtin_amdgcn_mfma_f32_16x16x32_bf16(a0, b0, acc2[0][0], 0, 0, 0);
      acc2[0][1] = __builtin_amdgcn_mfma_f32_16x16x32_bf16(a0, b1, acc2[0][1], 0, 0, 0);
      acc2[1][0] = __builtin_amdgcn_mfma_f32_16x16x32_bf16(a1, b0, acc2[1][0], 0, 0, 0);
      acc2[1][1] = __builtin_amdgcn_mfma_f32_16x16x32_bf16(a1, b1, acc2[1][1], 0, 0, 0);
    }
    __syncthreads();   // bar2: buf0 reads done; eg(next) staged; buf1 free (D done pre-bar1)

    // Phase C': ef (bf16) -> buf1
#pragma unroll
    for (int mt = 0; mt < 2; ++mt)
#pragma unroll
      for (int r = 0; r < 4; ++r) {
        buf1[wm * 32 + mt * 16 + rr + r][col0] = (__bf16)silu_f(acc2[mt][0][r] + bias2_0);
        buf1[wm * 32 + mt * 16 + rr + r][col1] = (__bf16)silu_f(acc2[mt][1][r] + bias2_1);
      }
    __syncthreads();   // bar3: buf1 ready

    // Phase D: segmented reduction (4 segments of 16 rows, 128 cols)
    {
      const int col = tid & 127, seg = tid >> 7, r0 = seg * 16;
      int curS = sp[gi0 + r0];
      float a = 0.f;
#pragma unroll 4
      for (int r = 0; r < 16; ++r) {
        const int s = sp[gi0 + r0 + r];
        if (s != curS) {
          unsafeAtomicAdd(&agg[(size_t)curS * HH + col], a);
          curS = s; a = 0.f;
        }
        a += (float)buf1[r0 + r][col];
      }
      unsafeAtomicAdd(&agg[(size_t)curS * HH + col], a);
    }
    // no trailing barrier: next Phase A writes buf0 only; bar1 fences buf1 reuse
  }
#undef PREFETCH
#undef STAGE_EG
}

// ---------------------------------------------------------------------------
// Node MLP via MFMA (8 waves, 16 cols/wave) + fused next-layer Ps/Pd
// ---------------------------------------------------------------------------
__global__ __launch_bounds__(512) void k_node(
    float* __restrict__ h, float* __restrict__ agg, const int* __restrict__ cnt,
    const u16* __restrict__ nwt1, const float* __restrict__ nb1,
    const u16* __restrict__ nwt2, const float* __restrict__ nb2,
    const float* __restrict__ cl, const int* __restrict__ n2g,
    u16* __restrict__ hbf,
    const u16* __restrict__ wt1s, const u16* __restrict__ wt1d,
    const float* __restrict__ Gl,
    float* __restrict__ Ps, float* __restrict__ Pd) {
  __shared__ __align__(16) __bf16 einp[32][264];
  __shared__ __align__(16) __bf16 t1n[32][136];
  const int tid = threadIdx.x, lane = tid & 63, w = tid >> 6;   // 8 waves
  const int lr = lane & 15, lk = (lane >> 4) * 8, rr = (lane >> 4) * 4;
  const int m = tid >> 4, p = tid & 15;    // staging: 16 threads per node
  const int n0 = blockIdx.x * 32;
  const int col = w * 16 + lr;             // each wave owns 16 cols
  {
    const int n = n0 + m;
    const uint4* hr = (const uint4*)(hbf + (size_t)n * 128);
    *(uint4*)(&einp[m][p * 8]) = hr[p];
    const float inv = 1.f / fmaxf((float)cnt[n], 1.f);
    const float4* ar = (const float4*)(agg + (size_t)n * 128);
    union { __bf16 b[8]; uint4 u; } tmp;
#pragma unroll
    for (int q = 0; q < 2; ++q) {
      const float4 v = ar[p * 2 + q];
      tmp.b[q * 4 + 0] = (__bf16)(v.x * inv);
      tmp.b[q * 4 + 1] = (__bf16)(v.y * inv);
      tmp.b[q * 4 + 2] = (__bf16)(v.z * inv);
      tmp.b[q * 4 + 3] = (__bf16)(v.w * inv);
    }
    *(uint4*)(&einp[m][128 + p * 8]) = tmp.u;
  }
  __syncthreads();
  f32x4 acc[2] = {};
  {
    const u16* w0 = nwt1 + (size_t)col * 256 + lk;
#pragma unroll
    for (int kb = 0; kb < 8; ++kb) {
      bf16x8 a0 = *(const bf16x8*)(&einp[lr][kb * 32 + lk]);
      bf16x8 a1 = *(const bf16x8*)(&einp[16 + lr][kb * 32 + lk]);
      bf16x8 b0 = *(const bf16x8*)(w0 + kb * 32);
      acc[0] = __builtin_amdgcn_mfma_f32_16x16x32_bf16(a0, b0, acc[0], 0, 0, 0);
      acc[1] = __builtin_amdgcn_mfma_f32_16x16x32_bf16(a1, b0, acc[1], 0, 0, 0);
    }
  }
  {
    const float bias = nb1[col];
#pragma unroll
    for (int mt = 0; mt < 2; ++mt)
#pragma unroll
      for (int r = 0; r < 4; ++r)
        t1n[mt * 16 + rr + r][col] = (__bf16)silu_f(acc[mt][r] + bias);
  }
  __syncthreads();
  f32x4 acc2[2] = {};
  {
    const u16* w0 = nwt2 + (size_t)col * 128 + lk;
#pragma unroll
    for (int kb = 0; kb < 4; ++kb) {
      bf16x8 a0 = *(const bf16x8*)(&t1n[lr][kb * 32 + lk]);
      bf16x8 a1 = *(const bf16x8*)(&t1n[16 + lr][kb * 32 + lk]);
      bf16x8 b0 = *(const bf16x8*)(w0 + kb * 32);
      acc2[0] = __builtin_amdgcn_mfma_f32_16x16x32_bf16(a0, b0, acc2[0], 0, 0, 0);
      acc2[1] = __builtin_amdgcn_mfma_f32_16x16x32_bf16(a1, b0, acc2[1], 0, 0, 0);
    }
  }
  __syncthreads();   // t1n reads done; safe to overwrite with new hbf
  {
    const float bias = nb2[col];
#pragma unroll
    for (int mt = 0; mt < 2; ++mt)
#pragma unroll
      for (int r = 0; r < 4; ++r) {
        const int row = mt * 16 + rr + r;
        const int n = n0 + row;
        const float rv = h[(size_t)n * 128 + col] + silu_f(acc2[mt][r] + bias)
                       + cl[(size_t)n2g[n] * 128 + col];
        h[(size_t)n * 128 + col] = rv;
        const u16 bf = f2bf(rv);
        hbf[(size_t)n * 128 + col] = bf;
        t1n[row][col] = *(const __bf16*)&bf;
        agg[(size_t)n * 128 + col] = 0.f;
      }
  }
  if (!wt1s) return;
  __syncthreads();   // new hbf in t1n ready
  f32x4 as[2] = {}, ad[2] = {};
  {
    const u16* ws0 = wt1s + (size_t)col * 128 + lk;
    const u16* wd0 = wt1d + (size_t)col * 128 + lk;
#pragma unroll
    for (int kb = 0; kb < 4; ++kb) {
      bf16x8 a0 = *(const bf16x8*)(&t1n[lr][kb * 32 + lk]);
      bf16x8 a1 = *(const bf16x8*)(&t1n[16 + lr][kb * 32 + lk]);
      bf16x8 bs0 = *(const bf16x8*)(ws0 + kb * 32);
      bf16x8 bd0 = *(const bf16x8*)(wd0 + kb * 32);
      as[0] = __builtin_amdgcn_mfma_f32_16x16x32_bf16(a0, bs0, as[0], 0, 0, 0);
      as[1] = __builtin_amdgcn_mfma_f32_16x16x32_bf16(a1, bs0, as[1], 0, 0, 0);
      ad[0] = __builtin_amdgcn_mfma_f32_16x16x32_bf16(a0, bd0, ad[0], 0, 0, 0);
      ad[1] = __builtin_amdgcn_mfma_f32_16x16x32_bf16(a1, bd0, ad[1], 0, 0, 0);
    }
  }
#pragma unroll
  for (int mt = 0; mt < 2; ++mt)
#pragma unroll
    for (int r = 0; r < 4; ++r) {
      const int n = n0 + mt * 16 + rr + r;
      Ps[(size_t)n * 128 + col] = as[mt][r] + Gl[(size_t)n2g[n] * 128 + col];
      Pd[(size_t)n * 128 + col] = ad[mt][r];
    }
}

// ---------------------------------------------------------------------------
// Output heads (coord + lattice fused)
// ---------------------------------------------------------------------------
__global__ __launch_bounds__(256) void k_heads(
    const float* __restrict__ h, const float* __restrict__ Wc,
    const float* __restrict__ Wl9, const float* __restrict__ lat,
    float* __restrict__ out) {
  const int b = blockIdx.x, tid = threadIdx.x;
  if (b < NN * 3 / 256) {
    const int idx = b * 256 + tid;
    const int n = idx / 3, j = idx % 3;
    float s = 0.f;
    for (int k = 0; k < 128; ++k) s += h[n * 128 + k] * Wc[k * 3 + j];
    out[BB * 9 + idx] = s;
    return;
  }
  const int g = b - NN * 3 / 256;
  __shared__ float part[2][128];
  __shared__ float gf[128];
  __shared__ float lo[9];
  const int c = tid & 127, half = tid >> 7;
  float s = 0.f;
  for (int mm = 0; mm < 16; ++mm)
    s += h[((size_t)g * 32 + half * 16 + mm) * 128 + c];
  part[half][c] = s;
  __syncthreads();
  if (tid < 128) gf[tid] = (part[0][tid] + part[1][tid]) * (1.f / 32.f);
  __syncthreads();
  if (tid < 9) {
    float t = 0.f;
    for (int k = 0; k < 128; ++k) t += gf[k] * Wl9[k * 9 + tid];
    lo[tid] = t;
  }
  __syncthreads();
  if (tid < 9) {
    const int i = tid / 3, kk = tid % 3;
    float t = 0.f;
#pragma unroll
    for (int j = 0; j < 3; ++j) t += lo[i * 3 + j] * lat[g * 9 + j * 3 + kk];
    out[g * 9 + tid] = t;
  }
}

// ---------------------------------------------------------------------------
extern "C" void kernel_launch(void* const* d_in, const int* in_sizes, int n_in,
                              void* d_out, int out_size, void* d_ws, size_t ws_size,
                              hipStream_t stream) {
  const int*   atom_types = (const int*)  d_in[0];
  const float* frac       = (const float*)d_in[1];
  const float* lattices   = (const float*)d_in[2];
  const float* z          = (const float*)d_in[3];
  const float* cemb       = (const float*)d_in[4];
  const int*   ei         = (const int*)  d_in[5];
  const int*   n2g        = (const int*)  d_in[6];
  const float* emb        = (const float*)d_in[7];
  const float* W_lat      = (const float*)d_in[8];
  const float* b_lat      = (const float*)d_in[9];
  const float* ew1        = (const float*)d_in[10];
  const float* eb1        = (const float*)d_in[11];
  const float* ew2        = (const float*)d_in[12];
  const float* eb2        = (const float*)d_in[13];
  const float* nw1        = (const float*)d_in[14];
  const float* nb1        = (const float*)d_in[15];
  const float* nw2        = (const float*)d_in[16];
  const float* nb2        = (const float*)d_in[17];
  const float* mixin      = (const float*)d_in[18];
  const float* aw1        = (const float*)d_in[19];
  const float* ab1        = (const float*)d_in[20];
  const float* aw2        = (const float*)d_in[21];
  const float* ab2        = (const float*)d_in[22];
  const float* Wc         = (const float*)d_in[23];
  const float* Wl9        = (const float*)d_in[24];
  float* out = (float*)d_out;

  uint8_t* base = (uint8_t*)d_ws;
  size_t off = 0;
  auto carve = [&](size_t bytes) -> void* {
    void* r = base + off;
    off = (off + bytes + 255) & ~(size_t)255;
    return r;
  };
  float* h      = (float*)carve((size_t)NN * HH * 4);
  u16*   hbf    = (u16*)  carve((size_t)NN * HH * 2);
  float* agg    = (float*)carve((size_t)NN * HH * 4);
  float* Ps     = (float*)carve((size_t)NN * HH * 4);
  float* Pd     = (float*)carve((size_t)NN * HH * 4);
  float* Gl     = (float*)carve((size_t)LL * BB * HH * 4);
  int*   cnt    = (int*)  carve((size_t)NN * 4);
  int*   cursor = (int*)  carve((size_t)NN * 4);
  int*   perm   = (int*)  carve((size_t)EE * 4);
  int*   sp     = (int*)  carve((size_t)EE * 4);
  int*   dp     = (int*)  carve((size_t)EE * 4);
  float* call   = (float*)carve((size_t)LL * BB * HH * 4);
  u16*   wt1s   = (u16*)  carve((size_t)R_WT1S * 2);
  u16*   wt1d   = (u16*)  carve((size_t)R_WT1D * 2);
  u16*   wt1g   = (u16*)  carve((size_t)R_WT1G * 2);
  u16*   wt2    = (u16*)  carve((size_t)R_WT2 * 2);
  u16*   nwt1   = (u16*)  carve((size_t)R_NWT1 * 2);
  u16*   nwt2   = (u16*)  carve((size_t)R_NWT2 * 2);
  u16*   hwt    = (u16*)  carve((size_t)R_HWT * 2);
  u16*   embbf  = (u16*)  carve((size_t)R_EMB * 2);
  u16*   zbf    = (u16*)  carve((size_t)R_Z * 2);

  hipMemsetAsync(cnt, 0, (size_t)NN * 4, stream);
  k_hist<<<EE / 256, 256, 0, stream>>>(ei, cnt);
  k_scan<<<1, 1024, 0, stream>>>(cnt, cursor);
  k_scatter<<<EE / 256, 256, 0, stream>>>(ei, cursor, perm);
  k_geo<<<EE / 256, 256, 0, stream>>>(perm, ei, sp, dp);
  k_prep<<<(PREP_TOT + 255) / 256, 256, 0, stream>>>(
      ew1, ew2, nw1, nw2, W_lat, emb, z,
      wt1s, wt1d, wt1g, wt2, nwt1, nwt2, hwt, embbf, zbf);
  k_gl<<<(LL * BB * 128 + 255) / 256, 256, 0, stream>>>(ew1, eb1, lattices, Gl);
  k_adapt<<<LL * BB, 128, 0, stream>>>(cemb, aw1, ab1, aw2, ab2, mixin, call);
  k_h0<<<NN / 32, 256, 0, stream>>>(atom_types, n2g, embbf, zbf, hwt, b_lat,
                                    wt1s, wt1d, Gl, h, hbf, Ps, Pd);
  hipMemsetAsync(agg, 0, (size_t)NN * HH * 4, stream);  // layers 1..3 zeroed by k_node

  for (int l = 0; l < LL; ++l) {
    k_edge<<<EE / (64 * TPB), 512, 0, stream>>>(Ps, Pd, frac, sp, dp,
        wt1g + (size_t)l * 128 * 64, wt2 + (size_t)l * 128 * 128,
        eb2 + l * 128, agg);
    const bool more = (l + 1 < LL);
    k_node<<<NN / 32, 512, 0, stream>>>(h, agg, cnt,
        nwt1 + (size_t)l * 128 * 256, nb1 + l * 128,
        nwt2 + (size_t)l * 128 * 128, nb2 + l * 128,
        call + (size_t)l * BB * HH, n2g, hbf,
        more ? wt1s + (size_t)(l + 1) * 128 * 128 : (const u16*)nullptr,
        more ? wt1d + (size_t)(l + 1) * 128 * 128 : (const u16*)nullptr,
        more ? Gl + (size_t)(l + 1) * BB * HH : (const float*)nullptr,
        Ps, Pd);
  }

  k_heads<<<NN * 3 / 256 + BB, 256, 0, stream>>>(h, Wc, Wl9, lattices, out);
}

// Round 14
// 264.523 us; speedup vs baseline: 1.5124x; 1.1533x over previous
//
#include <hip/hip_runtime.h>
#include <hip/hip_bf16.h>
#include <stdint.h>

#define NN 8192
#define BB 256
#define EE 163840
#define HH 128
#define ZZ 256
#define LL 4
#define TPB 5           // edge tiles (of 64) per block; 512 blocks * 5 * 64 = EE

typedef unsigned short u16;
typedef float  f32x4  __attribute__((ext_vector_type(4)));
typedef __bf16 bf16x8 __attribute__((ext_vector_type(8)));

__device__ __forceinline__ u16 f2bf(float f) {
  union { float f; uint32_t u; } v; v.f = f;
  uint32_t r = v.u + 0x7fffu + ((v.u >> 16) & 1u);   // RNE
  return (u16)(r >> 16);
}
__device__ __forceinline__ float silu_f(float x) {
  return x * __builtin_amdgcn_rcpf(1.0f + __expf(-x));
}

// ---------------------------------------------------------------------------
// Edge sorting prep: histogram -> exclusive scan -> scatter (fused geo)
// ---------------------------------------------------------------------------
__global__ void k_hist(const int* __restrict__ ei, int* __restrict__ cnt) {
  const int e = blockIdx.x * 256 + threadIdx.x;
  if (e < EE) atomicAdd(&cnt[ei[e]], 1);
}

__global__ __launch_bounds__(1024) void k_scan(const int* __restrict__ cnt,
                                               int* __restrict__ cursor) {
  __shared__ int part[1024];
  const int t = threadIdx.x;
  int v[8]; int s = 0;
#pragma unroll
  for (int j = 0; j < 8; ++j) { v[j] = s; s += cnt[t * 8 + j]; }
  part[t] = s;
  __syncthreads();
  for (int d = 1; d < 1024; d <<= 1) {
    int x = (t >= d) ? part[t - d] : 0;
    __syncthreads();
    part[t] += x;
    __syncthreads();
  }
  const int base = (t == 0) ? 0 : part[t - 1];
#pragma unroll
  for (int j = 0; j < 8; ++j) cursor[t * 8 + j] = base + v[j];
}

__global__ void k_scatter(const int* __restrict__ ei, int* __restrict__ cursor,
                          int* __restrict__ sp, int* __restrict__ dp) {
  const int e = blockIdx.x * 256 + threadIdx.x;
  if (e < EE) {
    const int s = ei[e], d = ei[EE + e];
    const int ppos = atomicAdd(&cursor[s], 1);
    sp[ppos] = s;
    dp[ppos] = d;
  }
}

// ---------------------------------------------------------------------------
// Fused prep: weight transposes + bf16 conversions + Gl
// ---------------------------------------------------------------------------
#define R_WT1S  (LL * 128 * 128)
#define R_WT1D  (LL * 128 * 128)
#define R_WT1G  (LL * 128 * 64)
#define R_WT2   (LL * 128 * 128)
#define R_NWT1  (LL * 128 * 256)
#define R_NWT2  (LL * 128 * 128)
#define R_HWT   (128 * 384)
#define R_EMB   (100 * 128)
#define R_Z     (BB * ZZ)
#define R_GL    (LL * BB * 128)
#define PREP_TOT (R_WT1S + R_WT1D + R_WT1G + R_WT2 + R_NWT1 + R_NWT2 + R_HWT + R_EMB + R_Z + R_GL)

__global__ __launch_bounds__(256) void k_prep(
    const float* __restrict__ ew1, const float* __restrict__ ew2,
    const float* __restrict__ nw1, const float* __restrict__ nw2,
    const float* __restrict__ Wl,  const float* __restrict__ emb,
    const float* __restrict__ z,   const float* __restrict__ eb1,
    const float* __restrict__ lat,
    u16* __restrict__ wt1s, u16* __restrict__ wt1d, u16* __restrict__ wt1g,
    u16* __restrict__ wt2,
    u16* __restrict__ nwt1, u16* __restrict__ nwt2,
    u16* __restrict__ hwt, u16* __restrict__ embbf, u16* __restrict__ zbf,
    float* __restrict__ Gl) {
  int idx = blockIdx.x * 256 + threadIdx.x;
  if (idx < R_WT1S) {
    const int l = idx >> 14, rem = idx & 16383;
    const int n = rem >> 7, k = rem & 127;
    wt1s[idx] = f2bf(ew1[((size_t)l * 325 + k) * 128 + n]);
    return;
  }
  idx -= R_WT1S;
  if (idx < R_WT1D) {
    const int l = idx >> 14, rem = idx & 16383;
    const int n = rem >> 7, k = rem & 127;
    wt1d[idx] = f2bf(ew1[((size_t)l * 325 + 128 + k) * 128 + n]);
    return;
  }
  idx -= R_WT1D;
  if (idx < R_WT1G) {
    const int l = idx >> 13, rem = idx & 8191;
    const int n = rem >> 6, kg = rem & 63;
    wt1g[idx] = (kg < 60) ? f2bf(ew1[((size_t)l * 325 + 256 + kg) * 128 + n]) : (u16)0;
    return;
  }
  idx -= R_WT1G;
  if (idx < R_WT2) {
    const int l = idx >> 14, rem = idx & 16383;
    const int n = rem >> 7, k = rem & 127;
    wt2[idx] = f2bf(ew2[((size_t)l * 128 + k) * 128 + n]);
    return;
  }
  idx -= R_WT2;
  if (idx < R_NWT1) {
    const int l = idx >> 15, rem = idx & 32767;
    const int n = rem >> 8, k = rem & 255;
    nwt1[idx] = f2bf(nw1[((size_t)l * 256 + k) * 128 + n]);
    return;
  }
  idx -= R_NWT1;
  if (idx < R_NWT2) {
    const int l = idx >> 14, rem = idx & 16383;
    const int n = rem >> 7, k = rem & 127;
    nwt2[idx] = f2bf(nw2[((size_t)l * 128 + k) * 128 + n]);
    return;
  }
  idx -= R_NWT2;
  if (idx < R_HWT) {
    const int n = idx / 384, k = idx % 384;
    hwt[idx] = f2bf(Wl[k * 128 + n]);
    return;
  }
  idx -= R_HWT;
  if (idx < R_EMB) { embbf[idx] = f2bf(emb[idx]); return; }
  idx -= R_EMB;
  if (idx < R_Z) { zbf[idx] = f2bf(z[idx]); return; }
  idx -= R_Z;
  if (idx < R_GL) {
    const int l = idx >> 15, rem = idx & 32767, g = rem >> 7, c = rem & 127;
    float s = eb1[l * 128 + c];
#pragma unroll
    for (int j = 0; j < 9; ++j) {
      const int i = j / 3, kk = j % 3;
      float lip = 0.f;
#pragma unroll
      for (int mm = 0; mm < 3; ++mm)
        lip += lat[g * 9 + i * 3 + mm] * lat[g * 9 + kk * 3 + mm];
      s += lip * ew1[((size_t)l * 325 + 316 + j) * 128 + c];
    }
    Gl[idx] = s;
  }
}

// per-layer, per-graph conditional adapter
__global__ __launch_bounds__(128) void k_adapt(
    const float* __restrict__ cemb, const float* __restrict__ aw1,
    const float* __restrict__ ab1, const float* __restrict__ aw2,
    const float* __restrict__ ab2, const float* __restrict__ mixin,
    float* __restrict__ call) {
  __shared__ float s1[128], s2[128];
  const int l = blockIdx.x >> 8, b = blockIdx.x & 255, c = threadIdx.x;
  const float ce = cemb[b];
  s1[c] = silu_f(ce * aw1[l * 128 + c] + ab1[l * 128 + c]);
  __syncthreads();
  float a = ab2[l * 128 + c];
  for (int k = 0; k < 128; ++k) a += s1[k] * aw2[(l * 128 + k) * 128 + c];
  s2[c] = silu_f(a);
  __syncthreads();
  float o = 0.f;
  for (int k = 0; k < 128; ++k) o += s2[k] * mixin[(l * 128 + k) * 128 + c];
  call[((size_t)l * 256 + b) * 128 + c] = o;
}

// ---------------------------------------------------------------------------
// h0 via MFMA + fused layer-0 Ps/Pd
// ---------------------------------------------------------------------------
__global__ __launch_bounds__(256) void k_h0(
    const int* __restrict__ at, const int* __restrict__ n2g,
    const u16* __restrict__ embbf, const u16* __restrict__ zbf,
    const u16* __restrict__ hwt, const float* __restrict__ bl,
    const u16* __restrict__ wt1s, const u16* __restrict__ wt1d,
    const float* __restrict__ Gl,
    float* __restrict__ h, u16* __restrict__ hbf,
    float* __restrict__ Ps, float* __restrict__ Pd) {
  __shared__ __align__(16) __bf16 einp[32][392];
  __bf16 (*hs)[136] = (__bf16(*)[136])&einp[0][0];
  const int tid = threadIdx.x, lane = tid & 63, w = tid >> 6;
  const int lr = lane & 15, lk = (lane >> 4) * 8, rr = (lane >> 4) * 4;
  const int m = tid >> 3, p = tid & 7;
  const int n0 = blockIdx.x * 32;
  {
    const int n = n0 + m;
    const uint4* er = (const uint4*)(embbf + (size_t)at[n] * 128);
    *(uint4*)(&einp[m][p * 16])     = er[p * 2];
    *(uint4*)(&einp[m][p * 16 + 8]) = er[p * 2 + 1];
    const uint4* zr = (const uint4*)(zbf + (size_t)n2g[n] * 256);
#pragma unroll
    for (int q = 0; q < 4; ++q)
      *(uint4*)(&einp[m][128 + p * 32 + q * 8]) = zr[p * 4 + q];
  }
  __syncthreads();
  f32x4 acc[2][2] = {};
  {
    const u16* w0 = hwt + (size_t)(w * 32 + lr) * 384 + lk;
    const u16* w1 = hwt + (size_t)(w * 32 + 16 + lr) * 384 + lk;
#pragma unroll
    for (int kb = 0; kb < 12; ++kb) {
      bf16x8 a0 = *(const bf16x8*)(&einp[lr][kb * 32 + lk]);
      bf16x8 a1 = *(const bf16x8*)(&einp[16 + lr][kb * 32 + lk]);
      bf16x8 b0 = *(const bf16x8*)(w0 + kb * 32);
      bf16x8 b1 = *(const bf16x8*)(w1 + kb * 32);
      acc[0][0] = __builtin_amdgcn_mfma_f32_16x16x32_bf16(a0, b0, acc[0][0], 0, 0, 0);
      acc[0][1] = __builtin_amdgcn_mfma_f32_16x16x32_bf16(a0, b1, acc[0][1], 0, 0, 0);
      acc[1][0] = __builtin_amdgcn_mfma_f32_16x16x32_bf16(a1, b0, acc[1][0], 0, 0, 0);
      acc[1][1] = __builtin_amdgcn_mfma_f32_16x16x32_bf16(a1, b1, acc[1][1], 0, 0, 0);
    }
  }
  __syncthreads();   // all einp reads done; safe to overlay hs
#pragma unroll
  for (int mt = 0; mt < 2; ++mt)
#pragma unroll
    for (int nt = 0; nt < 2; ++nt) {
      const int col = w * 32 + nt * 16 + lr;
      const float bias = bl[col];
#pragma unroll
      for (int r = 0; r < 4; ++r) {
        const int row = mt * 16 + rr + r;
        const float s = acc[mt][nt][r] + bias;
        h[(size_t)(n0 + row) * 128 + col] = s;
        const u16 bf = f2bf(s);
        hbf[(size_t)(n0 + row) * 128 + col] = bf;
        hs[row][col] = *(const __bf16*)&bf;
      }
    }
  __syncthreads();   // hs ready
  f32x4 as[2][2] = {}, ad[2][2] = {};
  {
    const u16* ws0 = wt1s + (size_t)(w * 32 + lr) * 128 + lk;
    const u16* ws1 = wt1s + (size_t)(w * 32 + 16 + lr) * 128 + lk;
    const u16* wd0 = wt1d + (size_t)(w * 32 + lr) * 128 + lk;
    const u16* wd1 = wt1d + (size_t)(w * 32 + 16 + lr) * 128 + lk;
#pragma unroll
    for (int kb = 0; kb < 4; ++kb) {
      bf16x8 a0 = *(const bf16x8*)(&hs[lr][kb * 32 + lk]);
      bf16x8 a1 = *(const bf16x8*)(&hs[16 + lr][kb * 32 + lk]);
      bf16x8 bs0 = *(const bf16x8*)(ws0 + kb * 32);
      bf16x8 bs1 = *(const bf16x8*)(ws1 + kb * 32);
      bf16x8 bd0 = *(const bf16x8*)(wd0 + kb * 32);
      bf16x8 bd1 = *(const bf16x8*)(wd1 + kb * 32);
      as[0][0] = __builtin_amdgcn_mfma_f32_16x16x32_bf16(a0, bs0, as[0][0], 0, 0, 0);
      as[0][1] = __builtin_amdgcn_mfma_f32_16x16x32_bf16(a0, bs1, as[0][1], 0, 0, 0);
      as[1][0] = __builtin_amdgcn_mfma_f32_16x16x32_bf16(a1, bs0, as[1][0], 0, 0, 0);
      as[1][1] = __builtin_amdgcn_mfma_f32_16x16x32_bf16(a1, bs1, as[1][1], 0, 0, 0);
      ad[0][0] = __builtin_amdgcn_mfma_f32_16x16x32_bf16(a0, bd0, ad[0][0], 0, 0, 0);
      ad[0][1] = __builtin_amdgcn_mfma_f32_16x16x32_bf16(a0, bd1, ad[0][1], 0, 0, 0);
      ad[1][0] = __builtin_amdgcn_mfma_f32_16x16x32_bf16(a1, bd0, ad[1][0], 0, 0, 0);
      ad[1][1] = __builtin_amdgcn_mfma_f32_16x16x32_bf16(a1, bd1, ad[1][1], 0, 0, 0);
    }
  }
#pragma unroll
  for (int mt = 0; mt < 2; ++mt)
#pragma unroll
    for (int nt = 0; nt < 2; ++nt) {
      const int col = w * 32 + nt * 16 + lr;
#pragma unroll
      for (int r = 0; r < 4; ++r) {
        const int n = n0 + mt * 16 + rr + r;
        Ps[(size_t)n * 128 + col] = as[mt][nt][r] + Gl[(size_t)n2g[n] * 128 + col];
        Pd[(size_t)n * 128 + col] = ad[mt][nt][r];
      }
    }
}

// ---------------------------------------------------------------------------
// Edge MLP (R8-faithful): inline Ps/Pd gathers from LDS srcs/dsts, single t1s
// buffer, eg staged in Phase B, 4 barriers/tile, TPB=5.
// ---------------------------------------------------------------------------
__global__ __launch_bounds__(512, 2) void k_edge(
    const float* __restrict__ Ps, const float* __restrict__ Pd,
    const float* __restrict__ fc,
    const int* __restrict__ sp, const int* __restrict__ dp,
    const u16* __restrict__ wt1g, const u16* __restrict__ wt2,
    const float* __restrict__ eb2, float* __restrict__ agg) {
  __shared__ __align__(16) __bf16 eg[64][72];      // 9216 B sin-emb (K=64)
  __shared__ __align__(16) __bf16 t1s[64][136];    // 17408 B (t1, then ef)
  __shared__ int srcs[2][64], dsts[2][64];

  const int tid = threadIdx.x;
  const int lane = tid & 63, w = tid >> 6;
  const int wm = w >> 2, wn = w & 3;          // 2 row-halves x 4 col-quarters
  const int lr = lane & 15, lk = (lane >> 4) * 8, rr = (lane >> 4) * 4;
  const int m = tid >> 3, p = tid & 7;        // staging: 8 threads per edge

  const u16* g0p  = wt1g + (size_t)(wn * 32 + lr) * 64 + lk;
  const u16* g1p  = wt1g + (size_t)(wn * 32 + 16 + lr) * 64 + lk;
  const u16* w2p0 = wt2 + (size_t)(wn * 32 + lr) * 128 + lk;
  const u16* w2p1 = wt2 + (size_t)(wn * 32 + 16 + lr) * 128 + lk;
  const float bias2_0 = eb2[wn * 32 + lr], bias2_1 = eb2[wn * 32 + 16 + lr];
  const int col0 = wn * 32 + lr, col1 = wn * 32 + 16 + lr;

  const int tile0 = blockIdx.x * TPB;

  // zero eg pad cols [60,72) once (never overwritten by staging)
  for (int i = tid; i < 64 * 12; i += 512) eg[i / 12][60 + i % 12] = (__bf16)0.0f;

  // prologue: stage tile0 (srcs/dsts/eg)
  {
    const int gi = tile0 * 64;
    const int s = sp[gi + m], d = dp[gi + m];
    if (p == 3) srcs[0][m] = s;
    if (p == 4) dsts[0][m] = d;
    if (p < 3) {
      float dd = fc[d * 3 + p] - fc[s * 3 + p];
      dd -= floorf(dd);
      float s1, c1;
      __sincosf(dd * 6.2831853071795864769f, &s1, &c1);
      eg[m][p * 10]      = (__bf16)0.0f;
      eg[m][30 + p * 10] = (__bf16)1.0f;
      float sk = s1, ck = c1;
#pragma unroll
      for (int k = 1; k < 10; ++k) {
        eg[m][p * 10 + k]      = (__bf16)sk;
        eg[m][30 + p * 10 + k] = (__bf16)ck;
        const float sn = sk * c1 + ck * s1, cn = ck * c1 - sk * s1;
        sk = sn; ck = cn;
      }
    }
  }
  __syncthreads();

  for (int t = 0; t < TPB; ++t) {
    const int cur = t & 1, nxt = cur ^ 1;
    const bool has_next = (t + 1 < TPB);

    // Phase A: inline acc init from Ps/Pd gathers + geo GEMM (K=64); t1 -> t1s
    {
      f32x4 acc[2][2];
#pragma unroll
      for (int mt = 0; mt < 2; ++mt)
#pragma unroll
        for (int r = 0; r < 4; ++r) {
          const int row = wm * 32 + mt * 16 + rr + r;
          const float* ps = Ps + (size_t)srcs[cur][row] * 128;
          const float* pd = Pd + (size_t)dsts[cur][row] * 128;
          acc[mt][0][r] = ps[col0] + pd[col0];
          acc[mt][1][r] = ps[col1] + pd[col1];
        }
      bf16x8 gb0[2], gb1[2];
      gb0[0] = *(const bf16x8*)(g0p);      gb0[1] = *(const bf16x8*)(g0p + 32);
      gb1[0] = *(const bf16x8*)(g1p);      gb1[1] = *(const bf16x8*)(g1p + 32);
#pragma unroll
      for (int kb = 0; kb < 2; ++kb) {
        bf16x8 a0 = *(const bf16x8*)(&eg[wm * 32 + lr][kb * 32 + lk]);
        bf16x8 a1 = *(const bf16x8*)(&eg[wm * 32 + 16 + lr][kb * 32 + lk]);
        acc[0][0] = __builtin_amdgcn_mfma_f32_16x16x32_bf16(a0, gb0[kb], acc[0][0], 0, 0, 0);
        acc[0][1] = __builtin_amdgcn_mfma_f32_16x16x32_bf16(a0, gb1[kb], acc[0][1], 0, 0, 0);
        acc[1][0] = __builtin_amdgcn_mfma_f32_16x16x32_bf16(a1, gb0[kb], acc[1][0], 0, 0, 0);
        acc[1][1] = __builtin_amdgcn_mfma_f32_16x16x32_bf16(a1, gb1[kb], acc[1][1], 0, 0, 0);
      }
#pragma unroll
      for (int mt = 0; mt < 2; ++mt)
#pragma unroll
        for (int r = 0; r < 4; ++r) {
          t1s[wm * 32 + mt * 16 + rr + r][col0] = (__bf16)silu_f(acc[mt][0][r]);
          t1s[wm * 32 + mt * 16 + rr + r][col1] = (__bf16)silu_f(acc[mt][1][r]);
        }
    }
    __syncthreads();   // bar1: eg(t) reads done; t1 visible in t1s

    // Phase B: stage next tile (srcs/dsts/eg); GEMM2 reads t1s -> regs
    if (has_next) {
      const int gi = (tile0 + t + 1) * 64;
      const int s = sp[gi + m], d = dp[gi + m];
      if (p == 3) srcs[nxt][m] = s;
      if (p == 4) dsts[nxt][m] = d;
      if (p < 3) {
        float dd = fc[d * 3 + p] - fc[s * 3 + p];
        dd -= floorf(dd);
        float s1, c1;
        __sincosf(dd * 6.2831853071795864769f, &s1, &c1);
        eg[m][p * 10]      = (__bf16)0.0f;
        eg[m][30 + p * 10] = (__bf16)1.0f;
        float sk = s1, ck = c1;
#pragma unroll
        for (int k = 1; k < 10; ++k) {
          eg[m][p * 10 + k]      = (__bf16)sk;
          eg[m][30 + p * 10 + k] = (__bf16)ck;
          const float sn = sk * c1 + ck * s1, cn = ck * c1 - sk * s1;
          sk = sn; ck = cn;
        }
      }
    }
    f32x4 acc2[2][2] = {};
#pragma unroll
    for (int kb = 0; kb < 4; ++kb) {
      bf16x8 a0 = *(const bf16x8*)(&t1s[wm * 32 + lr][kb * 32 + lk]);
      bf16x8 a1 = *(const bf16x8*)(&t1s[wm * 32 + 16 + lr][kb * 32 + lk]);
      bf16x8 b0 = *(const bf16x8*)(w2p0 + kb * 32);
      bf16x8 b1 = *(const bf16x8*)(w2p1 + kb * 32);
      acc2[0][0] = __builtin_amdgcn_mfma_f32_16x16x32_bf16(a0, b0, acc2[0][0], 0, 0, 0);
      acc2[0][1] = __builtin_amdgcn_mfma_f32_16x16x32_bf16(a0, b1, acc2[0][1], 0, 0, 0);
      acc2[1][0] = __builtin_amdgcn_mfma_f32_16x16x32_bf16(a1, b0, acc2[1][0], 0, 0, 0);
      acc2[1][1] = __builtin_amdgcn_mfma_f32_16x16x32_bf16(a1, b1, acc2[1][1], 0, 0, 0);
    }
    __syncthreads();   // bar2: t1s reads done; eg(next)/srcs/dsts staged

    // Phase C': ef (bf16) -> t1s
#pragma unroll
    for (int mt = 0; mt < 2; ++mt)
#pragma unroll
      for (int r = 0; r < 4; ++r) {
        t1s[wm * 32 + mt * 16 + rr + r][col0] = (__bf16)silu_f(acc2[mt][0][r] + bias2_0);
        t1s[wm * 32 + mt * 16 + rr + r][col1] = (__bf16)silu_f(acc2[mt][1][r] + bias2_1);
      }
    __syncthreads();   // bar3: ef visible

    // Phase D: segmented reduction (4 segments of 16 rows, 128 cols)
    {
      const int col = tid & 127, seg = tid >> 7, r0 = seg * 16;
      const int* sr = srcs[cur];
      int curS = sr[r0];
      float a = 0.f;
#pragma unroll 4
      for (int r = 0; r < 16; ++r) {
        const int s = sr[r0 + r];
        if (s != curS) {
          unsafeAtomicAdd(&agg[(size_t)curS * HH + col], a);
          curS = s; a = 0.f;
        }
        a += (float)t1s[r0 + r][col];
      }
      unsafeAtomicAdd(&agg[(size_t)curS * HH + col], a);
    }
    __syncthreads();   // bar4: t1s free for next tile's Phase A
  }
}

// ---------------------------------------------------------------------------
// Node MLP via MFMA (8 waves, 16 cols/wave) + fused next-layer Ps/Pd
// ---------------------------------------------------------------------------
__global__ __launch_bounds__(512) void k_node(
    float* __restrict__ h, float* __restrict__ agg, const int* __restrict__ cnt,
    const u16* __restrict__ nwt1, const float* __restrict__ nb1,
    const u16* __restrict__ nwt2, const float* __restrict__ nb2,
    const float* __restrict__ cl, const int* __restrict__ n2g,
    u16* __restrict__ hbf,
    const u16* __restrict__ wt1s, const u16* __restrict__ wt1d,
    const float* __restrict__ Gl,
    float* __restrict__ Ps, float* __restrict__ Pd) {
  __shared__ __align__(16) __bf16 einp[32][264];
  __shared__ __align__(16) __bf16 t1n[32][136];
  const int tid = threadIdx.x, lane = tid & 63, w = tid >> 6;   // 8 waves
  const int lr = lane & 15, lk = (lane >> 4) * 8, rr = (lane >> 4) * 4;
  const int m = tid >> 4, p = tid & 15;    // staging: 16 threads per node
  const int n0 = blockIdx.x * 32;
  const int col = w * 16 + lr;             // each wave owns 16 cols
  {
    const int n = n0 + m;
    const uint4* hr = (const uint4*)(hbf + (size_t)n * 128);
    *(uint4*)(&einp[m][p * 8]) = hr[p];
    const float inv = 1.f / fmaxf((float)cnt[n], 1.f);
    const float4* ar = (const float4*)(agg + (size_t)n * 128);
    union { __bf16 b[8]; uint4 u; } tmp;
#pragma unroll
    for (int q = 0; q < 2; ++q) {
      const float4 v = ar[p * 2 + q];
      tmp.b[q * 4 + 0] = (__bf16)(v.x * inv);
      tmp.b[q * 4 + 1] = (__bf16)(v.y * inv);
      tmp.b[q * 4 + 2] = (__bf16)(v.z * inv);
      tmp.b[q * 4 + 3] = (__bf16)(v.w * inv);
    }
    *(uint4*)(&einp[m][128 + p * 8]) = tmp.u;
  }
  __syncthreads();
  f32x4 acc[2] = {};
  {
    const u16* w0 = nwt1 + (size_t)col * 256 + lk;
#pragma unroll
    for (int kb = 0; kb < 8; ++kb) {
      bf16x8 a0 = *(const bf16x8*)(&einp[lr][kb * 32 + lk]);
      bf16x8 a1 = *(const bf16x8*)(&einp[16 + lr][kb * 32 + lk]);
      bf16x8 b0 = *(const bf16x8*)(w0 + kb * 32);
      acc[0] = __builtin_amdgcn_mfma_f32_16x16x32_bf16(a0, b0, acc[0], 0, 0, 0);
      acc[1] = __builtin_amdgcn_mfma_f32_16x16x32_bf16(a1, b0, acc[1], 0, 0, 0);
    }
  }
  {
    const float bias = nb1[col];
#pragma unroll
    for (int mt = 0; mt < 2; ++mt)
#pragma unroll
      for (int r = 0; r < 4; ++r)
        t1n[mt * 16 + rr + r][col] = (__bf16)silu_f(acc[mt][r] + bias);
  }
  __syncthreads();
  f32x4 acc2[2] = {};
  {
    const u16* w0 = nwt2 + (size_t)col * 128 + lk;
#pragma unroll
    for (int kb = 0; kb < 4; ++kb) {
      bf16x8 a0 = *(const bf16x8*)(&t1n[lr][kb * 32 + lk]);
      bf16x8 a1 = *(const bf16x8*)(&t1n[16 + lr][kb * 32 + lk]);
      bf16x8 b0 = *(const bf16x8*)(w0 + kb * 32);
      acc2[0] = __builtin_amdgcn_mfma_f32_16x16x32_bf16(a0, b0, acc2[0], 0, 0, 0);
      acc2[1] = __builtin_amdgcn_mfma_f32_16x16x32_bf16(a1, b0, acc2[1], 0, 0, 0);
    }
  }
  __syncthreads();   // t1n reads done; safe to overwrite with new hbf
  {
    const float bias = nb2[col];
#pragma unroll
    for (int mt = 0; mt < 2; ++mt)
#pragma unroll
      for (int r = 0; r < 4; ++r) {
        const int row = mt * 16 + rr + r;
        const int n = n0 + row;
        const float rv = h[(size_t)n * 128 + col] + silu_f(acc2[mt][r] + bias)
                       + cl[(size_t)n2g[n] * 128 + col];
        h[(size_t)n * 128 + col] = rv;
        const u16 bf = f2bf(rv);
        hbf[(size_t)n * 128 + col] = bf;
        t1n[row][col] = *(const __bf16*)&bf;
        agg[(size_t)n * 128 + col] = 0.f;
      }
  }
  if (!wt1s) return;
  __syncthreads();   // new hbf in t1n ready
  f32x4 as[2] = {}, ad[2] = {};
  {
    const u16* ws0 = wt1s + (size_t)col * 128 + lk;
    const u16* wd0 = wt1d + (size_t)col * 128 + lk;
#pragma unroll
    for (int kb = 0; kb < 4; ++kb) {
      bf16x8 a0 = *(const bf16x8*)(&t1n[lr][kb * 32 + lk]);
      bf16x8 a1 = *(const bf16x8*)(&t1n[16 + lr][kb * 32 + lk]);
      bf16x8 bs0 = *(const bf16x8*)(ws0 + kb * 32);
      bf16x8 bd0 = *(const bf16x8*)(wd0 + kb * 32);
      as[0] = __builtin_amdgcn_mfma_f32_16x16x32_bf16(a0, bs0, as[0], 0, 0, 0);
      as[1] = __builtin_amdgcn_mfma_f32_16x16x32_bf16(a1, bs0, as[1], 0, 0, 0);
      ad[0] = __builtin_amdgcn_mfma_f32_16x16x32_bf16(a0, bd0, ad[0], 0, 0, 0);
      ad[1] = __builtin_amdgcn_mfma_f32_16x16x32_bf16(a1, bd0, ad[1], 0, 0, 0);
    }
  }
#pragma unroll
  for (int mt = 0; mt < 2; ++mt)
#pragma unroll
    for (int r = 0; r < 4; ++r) {
      const int n = n0 + mt * 16 + rr + r;
      Ps[(size_t)n * 128 + col] = as[mt][r] + Gl[(size_t)n2g[n] * 128 + col];
      Pd[(size_t)n * 128 + col] = ad[mt][r];
    }
}

// ---------------------------------------------------------------------------
// Output heads (coord + lattice fused)
// ---------------------------------------------------------------------------
__global__ __launch_bounds__(256) void k_heads(
    const float* __restrict__ h, const float* __restrict__ Wc,
    const float* __restrict__ Wl9, const float* __restrict__ lat,
    float* __restrict__ out) {
  const int b = blockIdx.x, tid = threadIdx.x;
  if (b < NN * 3 / 256) {
    const int idx = b * 256 + tid;
    const int n = idx / 3, j = idx % 3;
    float s = 0.f;
    for (int k = 0; k < 128; ++k) s += h[n * 128 + k] * Wc[k * 3 + j];
    out[BB * 9 + idx] = s;
    return;
  }
  const int g = b - NN * 3 / 256;
  __shared__ float part[2][128];
  __shared__ float gf[128];
  __shared__ float lo[9];
  const int c = tid & 127, half = tid >> 7;
  float s = 0.f;
  for (int mm = 0; mm < 16; ++mm)
    s += h[((size_t)g * 32 + half * 16 + mm) * 128 + c];
  part[half][c] = s;
  __syncthreads();
  if (tid < 128) gf[tid] = (part[0][tid] + part[1][tid]) * (1.f / 32.f);
  __syncthreads();
  if (tid < 9) {
    float t = 0.f;
    for (int k = 0; k < 128; ++k) t += gf[k] * Wl9[k * 9 + tid];
    lo[tid] = t;
  }
  __syncthreads();
  if (tid < 9) {
    const int i = tid / 3, kk = tid % 3;
    float t = 0.f;
#pragma unroll
    for (int j = 0; j < 3; ++j) t += lo[i * 3 + j] * lat[g * 9 + j * 3 + kk];
    out[g * 9 + tid] = t;
  }
}

// ---------------------------------------------------------------------------
extern "C" void kernel_launch(void* const* d_in, const int* in_sizes, int n_in,
                              void* d_out, int out_size, void* d_ws, size_t ws_size,
                              hipStream_t stream) {
  const int*   atom_types = (const int*)  d_in[0];
  const float* frac       = (const float*)d_in[1];
  const float* lattices   = (const float*)d_in[2];
  const float* z          = (const float*)d_in[3];
  const float* cemb       = (const float*)d_in[4];
  const int*   ei         = (const int*)  d_in[5];
  const int*   n2g        = (const int*)  d_in[6];
  const float* emb        = (const float*)d_in[7];
  const float* W_lat      = (const float*)d_in[8];
  const float* b_lat      = (const float*)d_in[9];
  const float* ew1        = (const float*)d_in[10];
  const float* eb1        = (const float*)d_in[11];
  const float* ew2        = (const float*)d_in[12];
  const float* eb2        = (const float*)d_in[13];
  const float* nw1        = (const float*)d_in[14];
  const float* nb1        = (const float*)d_in[15];
  const float* nw2        = (const float*)d_in[16];
  const float* nb2        = (const float*)d_in[17];
  const float* mixin      = (const float*)d_in[18];
  const float* aw1        = (const float*)d_in[19];
  const float* ab1        = (const float*)d_in[20];
  const float* aw2        = (const float*)d_in[21];
  const float* ab2        = (const float*)d_in[22];
  const float* Wc         = (const float*)d_in[23];
  const float* Wl9        = (const float*)d_in[24];
  float* out = (float*)d_out;

  uint8_t* base = (uint8_t*)d_ws;
  size_t off = 0;
  auto carve = [&](size_t bytes) -> void* {
    void* r = base + off;
    off = (off + bytes + 255) & ~(size_t)255;
    return r;
  };
  float* h      = (float*)carve((size_t)NN * HH * 4);
  u16*   hbf    = (u16*)  carve((size_t)NN * HH * 2);
  float* agg    = (float*)carve((size_t)NN * HH * 4);
  float* Ps     = (float*)carve((size_t)NN * HH * 4);
  float* Pd     = (float*)carve((size_t)NN * HH * 4);
  float* Gl     = (float*)carve((size_t)LL * BB * HH * 4);
  int*   cnt    = (int*)  carve((size_t)NN * 4);
  int*   cursor = (int*)  carve((size_t)NN * 4);
  int*   sp     = (int*)  carve((size_t)EE * 4);
  int*   dp     = (int*)  carve((size_t)EE * 4);
  float* call   = (float*)carve((size_t)LL * BB * HH * 4);
  u16*   wt1s   = (u16*)  carve((size_t)R_WT1S * 2);
  u16*   wt1d   = (u16*)  carve((size_t)R_WT1D * 2);
  u16*   wt1g   = (u16*)  carve((size_t)R_WT1G * 2);
  u16*   wt2    = (u16*)  carve((size_t)R_WT2 * 2);
  u16*   nwt1   = (u16*)  carve((size_t)R_NWT1 * 2);
  u16*   nwt2   = (u16*)  carve((size_t)R_NWT2 * 2);
  u16*   hwt    = (u16*)  carve((size_t)R_HWT * 2);
  u16*   embbf  = (u16*)  carve((size_t)R_EMB * 2);
  u16*   zbf    = (u16*)  carve((size_t)R_Z * 2);

  hipMemsetAsync(cnt, 0, (size_t)NN * 4, stream);
  k_hist<<<EE / 256, 256, 0, stream>>>(ei, cnt);
  k_scan<<<1, 1024, 0, stream>>>(cnt, cursor);
  k_scatter<<<EE / 256, 256, 0, stream>>>(ei, cursor, sp, dp);
  k_prep<<<(PREP_TOT + 255) / 256, 256, 0, stream>>>(
      ew1, ew2, nw1, nw2, W_lat, emb, z, eb1, lattices,
      wt1s, wt1d, wt1g, wt2, nwt1, nwt2, hwt, embbf, zbf, Gl);
  k_adapt<<<LL * BB, 128, 0, stream>>>(cemb, aw1, ab1, aw2, ab2, mixin, call);
  k_h0<<<NN / 32, 256, 0, stream>>>(atom_types, n2g, embbf, zbf, hwt, b_lat,
                                    wt1s, wt1d, Gl, h, hbf, Ps, Pd);
  hipMemsetAsync(agg, 0, (size_t)NN * HH * 4, stream);  // layers 1..3 zeroed by k_node

  for (int l = 0; l < LL; ++l) {
    k_edge<<<EE / (64 * TPB), 512, 0, stream>>>(Ps, Pd, frac, sp, dp,
        wt1g + (size_t)l * 128 * 64, wt2 + (size_t)l * 128 * 128,
        eb2 + l * 128, agg);
    const bool more = (l + 1 < LL);
    k_node<<<NN / 32, 512, 0, stream>>>(h, agg, cnt,
        nwt1 + (size_t)l * 128 * 256, nb1 + l * 128,
        nwt2 + (size_t)l * 128 * 128, nb2 + l * 128,
        call + (size_t)l * BB * HH, n2g, hbf,
        more ? wt1s + (size_t)(l + 1) * 128 * 128 : (const u16*)nullptr,
        more ? wt1d + (size_t)(l + 1) * 128 * 128 : (const u16*)nullptr,
        more ? Gl + (size_t)(l + 1) * BB * HH : (const float*)nullptr,
        Ps, Pd);
  }

  k_heads<<<NN * 3 / 256 + BB, 256, 0, stream>>>(h, Wc, Wl9, lattices, out);
}

// Round 15
// 262.730 us; speedup vs baseline: 1.5227x; 1.0068x over previous
//
#include <hip/hip_runtime.h>
#include <hip/hip_bf16.h>
#include <stdint.h>

#define NN 8192
#define BB 256
#define EE 163840
#define HH 128
#define ZZ 256
#define LL 4
#define TPB 5           // edge tiles (of 64) per block; 512 blocks * 5 * 64 = EE

typedef unsigned short u16;
typedef float  f32x4  __attribute__((ext_vector_type(4)));
typedef __bf16 bf16x8 __attribute__((ext_vector_type(8)));

__device__ __forceinline__ u16 f2bf(float f) {
  union { float f; uint32_t u; } v; v.f = f;
  uint32_t r = v.u + 0x7fffu + ((v.u >> 16) & 1u);   // RNE
  return (u16)(r >> 16);
}
__device__ __forceinline__ float silu_f(float x) {
  return x * __builtin_amdgcn_rcpf(1.0f + __expf(-x));
}

// ---------------------------------------------------------------------------
// Edge sorting prep: histogram -> exclusive scan -> scatter (fused geo)
// ---------------------------------------------------------------------------
__global__ void k_hist(const int* __restrict__ ei, int* __restrict__ cnt) {
  const int e = blockIdx.x * 256 + threadIdx.x;
  if (e < EE) atomicAdd(&cnt[ei[e]], 1);
}

__global__ __launch_bounds__(1024) void k_scan(const int* __restrict__ cnt,
                                               int* __restrict__ cursor) {
  __shared__ int part[1024];
  const int t = threadIdx.x;
  int v[8]; int s = 0;
#pragma unroll
  for (int j = 0; j < 8; ++j) { v[j] = s; s += cnt[t * 8 + j]; }
  part[t] = s;
  __syncthreads();
  for (int d = 1; d < 1024; d <<= 1) {
    int x = (t >= d) ? part[t - d] : 0;
    __syncthreads();
    part[t] += x;
    __syncthreads();
  }
  const int base = (t == 0) ? 0 : part[t - 1];
#pragma unroll
  for (int j = 0; j < 8; ++j) cursor[t * 8 + j] = base + v[j];
}

__global__ void k_scatter(const int* __restrict__ ei, int* __restrict__ cursor,
                          int* __restrict__ sp, int* __restrict__ dp) {
  const int e = blockIdx.x * 256 + threadIdx.x;
  if (e < EE) {
    const int s = ei[e], d = ei[EE + e];
    const int ppos = atomicAdd(&cursor[s], 1);
    sp[ppos] = s;
    dp[ppos] = d;
  }
}

// ---------------------------------------------------------------------------
// Fused prep: weight transposes + bf16 conversions + Gl
// ---------------------------------------------------------------------------
#define R_WT1S  (LL * 128 * 128)
#define R_WT1D  (LL * 128 * 128)
#define R_WT1G  (LL * 128 * 64)
#define R_WT2   (LL * 128 * 128)
#define R_NWT1  (LL * 128 * 256)
#define R_NWT2  (LL * 128 * 128)
#define R_HWT   (128 * 384)
#define R_EMB   (100 * 128)
#define R_Z     (BB * ZZ)
#define R_GL    (LL * BB * 128)
#define PREP_TOT (R_WT1S + R_WT1D + R_WT1G + R_WT2 + R_NWT1 + R_NWT2 + R_HWT + R_EMB + R_Z + R_GL)

__global__ __launch_bounds__(256) void k_prep(
    const float* __restrict__ ew1, const float* __restrict__ ew2,
    const float* __restrict__ nw1, const float* __restrict__ nw2,
    const float* __restrict__ Wl,  const float* __restrict__ emb,
    const float* __restrict__ z,   const float* __restrict__ eb1,
    const float* __restrict__ lat,
    u16* __restrict__ wt1s, u16* __restrict__ wt1d, u16* __restrict__ wt1g,
    u16* __restrict__ wt2,
    u16* __restrict__ nwt1, u16* __restrict__ nwt2,
    u16* __restrict__ hwt, u16* __restrict__ embbf, u16* __restrict__ zbf,
    float* __restrict__ Gl) {
  int idx = blockIdx.x * 256 + threadIdx.x;
  if (idx < R_WT1S) {
    const int l = idx >> 14, rem = idx & 16383;
    const int n = rem >> 7, k = rem & 127;
    wt1s[idx] = f2bf(ew1[((size_t)l * 325 + k) * 128 + n]);
    return;
  }
  idx -= R_WT1S;
  if (idx < R_WT1D) {
    const int l = idx >> 14, rem = idx & 16383;
    const int n = rem >> 7, k = rem & 127;
    wt1d[idx] = f2bf(ew1[((size_t)l * 325 + 128 + k) * 128 + n]);
    return;
  }
  idx -= R_WT1D;
  if (idx < R_WT1G) {
    const int l = idx >> 13, rem = idx & 8191;
    const int n = rem >> 6, kg = rem & 63;
    wt1g[idx] = (kg < 60) ? f2bf(ew1[((size_t)l * 325 + 256 + kg) * 128 + n]) : (u16)0;
    return;
  }
  idx -= R_WT1G;
  if (idx < R_WT2) {
    const int l = idx >> 14, rem = idx & 16383;
    const int n = rem >> 7, k = rem & 127;
    wt2[idx] = f2bf(ew2[((size_t)l * 128 + k) * 128 + n]);
    return;
  }
  idx -= R_WT2;
  if (idx < R_NWT1) {
    const int l = idx >> 15, rem = idx & 32767;
    const int n = rem >> 8, k = rem & 255;
    nwt1[idx] = f2bf(nw1[((size_t)l * 256 + k) * 128 + n]);
    return;
  }
  idx -= R_NWT1;
  if (idx < R_NWT2) {
    const int l = idx >> 14, rem = idx & 16383;
    const int n = rem >> 7, k = rem & 127;
    nwt2[idx] = f2bf(nw2[((size_t)l * 128 + k) * 128 + n]);
    return;
  }
  idx -= R_NWT2;
  if (idx < R_HWT) {
    const int n = idx / 384, k = idx % 384;
    hwt[idx] = f2bf(Wl[k * 128 + n]);
    return;
  }
  idx -= R_HWT;
  if (idx < R_EMB) { embbf[idx] = f2bf(emb[idx]); return; }
  idx -= R_EMB;
  if (idx < R_Z) { zbf[idx] = f2bf(z[idx]); return; }
  idx -= R_Z;
  if (idx < R_GL) {
    const int l = idx >> 15, rem = idx & 32767, g = rem >> 7, c = rem & 127;
    float s = eb1[l * 128 + c];
#pragma unroll
    for (int j = 0; j < 9; ++j) {
      const int i = j / 3, kk = j % 3;
      float lip = 0.f;
#pragma unroll
      for (int mm = 0; mm < 3; ++mm)
        lip += lat[g * 9 + i * 3 + mm] * lat[g * 9 + kk * 3 + mm];
      s += lip * ew1[((size_t)l * 325 + 316 + j) * 128 + c];
    }
    Gl[idx] = s;
  }
}

// per-layer, per-graph conditional adapter
__global__ __launch_bounds__(128) void k_adapt(
    const float* __restrict__ cemb, const float* __restrict__ aw1,
    const float* __restrict__ ab1, const float* __restrict__ aw2,
    const float* __restrict__ ab2, const float* __restrict__ mixin,
    float* __restrict__ call) {
  __shared__ float s1[128], s2[128];
  const int l = blockIdx.x >> 8, b = blockIdx.x & 255, c = threadIdx.x;
  const float ce = cemb[b];
  s1[c] = silu_f(ce * aw1[l * 128 + c] + ab1[l * 128 + c]);
  __syncthreads();
  float a = ab2[l * 128 + c];
  for (int k = 0; k < 128; ++k) a += s1[k] * aw2[(l * 128 + k) * 128 + c];
  s2[c] = silu_f(a);
  __syncthreads();
  float o = 0.f;
  for (int k = 0; k < 128; ++k) o += s2[k] * mixin[(l * 128 + k) * 128 + c];
  call[((size_t)l * 256 + b) * 128 + c] = o;
}

// ---------------------------------------------------------------------------
// h0 via MFMA + fused layer-0 Ps/Pd
// ---------------------------------------------------------------------------
__global__ __launch_bounds__(256) void k_h0(
    const int* __restrict__ at, const int* __restrict__ n2g,
    const u16* __restrict__ embbf, const u16* __restrict__ zbf,
    const u16* __restrict__ hwt, const float* __restrict__ bl,
    const u16* __restrict__ wt1s, const u16* __restrict__ wt1d,
    const float* __restrict__ Gl,
    float* __restrict__ h, u16* __restrict__ hbf,
    float* __restrict__ Ps, float* __restrict__ Pd) {
  __shared__ __align__(16) __bf16 einp[32][392];
  __bf16 (*hs)[136] = (__bf16(*)[136])&einp[0][0];
  const int tid = threadIdx.x, lane = tid & 63, w = tid >> 6;
  const int lr = lane & 15, lk = (lane >> 4) * 8, rr = (lane >> 4) * 4;
  const int m = tid >> 3, p = tid & 7;
  const int n0 = blockIdx.x * 32;
  {
    const int n = n0 + m;
    const uint4* er = (const uint4*)(embbf + (size_t)at[n] * 128);
    *(uint4*)(&einp[m][p * 16])     = er[p * 2];
    *(uint4*)(&einp[m][p * 16 + 8]) = er[p * 2 + 1];
    const uint4* zr = (const uint4*)(zbf + (size_t)n2g[n] * 256);
#pragma unroll
    for (int q = 0; q < 4; ++q)
      *(uint4*)(&einp[m][128 + p * 32 + q * 8]) = zr[p * 4 + q];
  }
  __syncthreads();
  f32x4 acc[2][2] = {};
  {
    const u16* w0 = hwt + (size_t)(w * 32 + lr) * 384 + lk;
    const u16* w1 = hwt + (size_t)(w * 32 + 16 + lr) * 384 + lk;
#pragma unroll
    for (int kb = 0; kb < 12; ++kb) {
      bf16x8 a0 = *(const bf16x8*)(&einp[lr][kb * 32 + lk]);
      bf16x8 a1 = *(const bf16x8*)(&einp[16 + lr][kb * 32 + lk]);
      bf16x8 b0 = *(const bf16x8*)(w0 + kb * 32);
      bf16x8 b1 = *(const bf16x8*)(w1 + kb * 32);
      acc[0][0] = __builtin_amdgcn_mfma_f32_16x16x32_bf16(a0, b0, acc[0][0], 0, 0, 0);
      acc[0][1] = __builtin_amdgcn_mfma_f32_16x16x32_bf16(a0, b1, acc[0][1], 0, 0, 0);
      acc[1][0] = __builtin_amdgcn_mfma_f32_16x16x32_bf16(a1, b0, acc[1][0], 0, 0, 0);
      acc[1][1] = __builtin_amdgcn_mfma_f32_16x16x32_bf16(a1, b1, acc[1][1], 0, 0, 0);
    }
  }
  __syncthreads();   // all einp reads done; safe to overlay hs
#pragma unroll
  for (int mt = 0; mt < 2; ++mt)
#pragma unroll
    for (int nt = 0; nt < 2; ++nt) {
      const int col = w * 32 + nt * 16 + lr;
      const float bias = bl[col];
#pragma unroll
      for (int r = 0; r < 4; ++r) {
        const int row = mt * 16 + rr + r;
        const float s = acc[mt][nt][r] + bias;
        h[(size_t)(n0 + row) * 128 + col] = s;
        const u16 bf = f2bf(s);
        hbf[(size_t)(n0 + row) * 128 + col] = bf;
        hs[row][col] = *(const __bf16*)&bf;
      }
    }
  __syncthreads();   // hs ready
  f32x4 as[2][2] = {}, ad[2][2] = {};
  {
    const u16* ws0 = wt1s + (size_t)(w * 32 + lr) * 128 + lk;
    const u16* ws1 = wt1s + (size_t)(w * 32 + 16 + lr) * 128 + lk;
    const u16* wd0 = wt1d + (size_t)(w * 32 + lr) * 128 + lk;
    const u16* wd1 = wt1d + (size_t)(w * 32 + 16 + lr) * 128 + lk;
#pragma unroll
    for (int kb = 0; kb < 4; ++kb) {
      bf16x8 a0 = *(const bf16x8*)(&hs[lr][kb * 32 + lk]);
      bf16x8 a1 = *(const bf16x8*)(&hs[16 + lr][kb * 32 + lk]);
      bf16x8 bs0 = *(const bf16x8*)(ws0 + kb * 32);
      bf16x8 bs1 = *(const bf16x8*)(ws1 + kb * 32);
      bf16x8 bd0 = *(const bf16x8*)(wd0 + kb * 32);
      bf16x8 bd1 = *(const bf16x8*)(wd1 + kb * 32);
      as[0][0] = __builtin_amdgcn_mfma_f32_16x16x32_bf16(a0, bs0, as[0][0], 0, 0, 0);
      as[0][1] = __builtin_amdgcn_mfma_f32_16x16x32_bf16(a0, bs1, as[0][1], 0, 0, 0);
      as[1][0] = __builtin_amdgcn_mfma_f32_16x16x32_bf16(a1, bs0, as[1][0], 0, 0, 0);
      as[1][1] = __builtin_amdgcn_mfma_f32_16x16x32_bf16(a1, bs1, as[1][1], 0, 0, 0);
      ad[0][0] = __builtin_amdgcn_mfma_f32_16x16x32_bf16(a0, bd0, ad[0][0], 0, 0, 0);
      ad[0][1] = __builtin_amdgcn_mfma_f32_16x16x32_bf16(a0, bd1, ad[0][1], 0, 0, 0);
      ad[1][0] = __builtin_amdgcn_mfma_f32_16x16x32_bf16(a1, bd0, ad[1][0], 0, 0, 0);
      ad[1][1] = __builtin_amdgcn_mfma_f32_16x16x32_bf16(a1, bd1, ad[1][1], 0, 0, 0);
    }
  }
#pragma unroll
  for (int mt = 0; mt < 2; ++mt)
#pragma unroll
    for (int nt = 0; nt < 2; ++nt) {
      const int col = w * 32 + nt * 16 + lr;
#pragma unroll
      for (int r = 0; r < 4; ++r) {
        const int n = n0 + mt * 16 + rr + r;
        Ps[(size_t)n * 128 + col] = as[mt][nt][r] + Gl[(size_t)n2g[n] * 128 + col];
        Pd[(size_t)n * 128 + col] = ad[mt][nt][r];
      }
    }
}

// ---------------------------------------------------------------------------
// Edge MLP (R14 structure + T14 gather prefetch at Phase C').
// ---------------------------------------------------------------------------
__global__ __launch_bounds__(512, 2) void k_edge(
    const float* __restrict__ Ps, const float* __restrict__ Pd,
    const float* __restrict__ fc,
    const int* __restrict__ sp, const int* __restrict__ dp,
    const u16* __restrict__ wt1g, const u16* __restrict__ wt2,
    const float* __restrict__ eb2, float* __restrict__ agg) {
  __shared__ __align__(16) __bf16 eg[64][72];      // 9216 B sin-emb (K=64)
  __shared__ __align__(16) __bf16 t1s[64][136];    // 17408 B (t1, then ef)
  __shared__ int srcs[2][64], dsts[2][64];

  const int tid = threadIdx.x;
  const int lane = tid & 63, w = tid >> 6;
  const int wm = w >> 2, wn = w & 3;          // 2 row-halves x 4 col-quarters
  const int lr = lane & 15, lk = (lane >> 4) * 8, rr = (lane >> 4) * 4;
  const int m = tid >> 3, p = tid & 7;        // staging: 8 threads per edge

  const u16* g0p  = wt1g + (size_t)(wn * 32 + lr) * 64 + lk;
  const u16* g1p  = wt1g + (size_t)(wn * 32 + 16 + lr) * 64 + lk;
  const u16* w2p0 = wt2 + (size_t)(wn * 32 + lr) * 128 + lk;
  const u16* w2p1 = wt2 + (size_t)(wn * 32 + 16 + lr) * 128 + lk;
  const float bias2_0 = eb2[wn * 32 + lr], bias2_1 = eb2[wn * 32 + 16 + lr];
  const int col0 = wn * 32 + lr, col1 = wn * 32 + 16 + lr;

  const int tile0 = blockIdx.x * TPB;

  // T14: gathers for the upcoming tile, issued as early as indices allow
  float pre[2][2][4];
#define PREFETCH(buf) { \
  _Pragma("unroll") \
  for (int mt = 0; mt < 2; ++mt) \
    _Pragma("unroll") \
    for (int r = 0; r < 4; ++r) { \
      const int row = wm * 32 + mt * 16 + rr + r; \
      const float* ps = Ps + (size_t)srcs[buf][row] * 128; \
      const float* pd = Pd + (size_t)dsts[buf][row] * 128; \
      pre[mt][0][r] = ps[col0] + pd[col0]; \
      pre[mt][1][r] = ps[col1] + pd[col1]; \
    } }

  // zero eg pad cols [60,72) once (never overwritten by staging)
  for (int i = tid; i < 64 * 12; i += 512) eg[i / 12][60 + i % 12] = (__bf16)0.0f;

  // prologue: stage tile0 (srcs/dsts/eg)
  {
    const int gi = tile0 * 64;
    const int s = sp[gi + m], d = dp[gi + m];
    if (p == 3) srcs[0][m] = s;
    if (p == 4) dsts[0][m] = d;
    if (p < 3) {
      float dd = fc[d * 3 + p] - fc[s * 3 + p];
      dd -= floorf(dd);
      float s1, c1;
      __sincosf(dd * 6.2831853071795864769f, &s1, &c1);
      eg[m][p * 10]      = (__bf16)0.0f;
      eg[m][30 + p * 10] = (__bf16)1.0f;
      float sk = s1, ck = c1;
#pragma unroll
      for (int k = 1; k < 10; ++k) {
        eg[m][p * 10 + k]      = (__bf16)sk;
        eg[m][30 + p * 10 + k] = (__bf16)ck;
        const float sn = sk * c1 + ck * s1, cn = ck * c1 - sk * s1;
        sk = sn; ck = cn;
      }
    }
  }
  __syncthreads();
  PREFETCH(0);   // tile0 gathers (exposed once per block)

  for (int t = 0; t < TPB; ++t) {
    const int cur = t & 1, nxt = cur ^ 1;
    const bool has_next = (t + 1 < TPB);

    // Phase A: acc init from prefetched regs + geo GEMM (K=64); t1 -> t1s
    {
      f32x4 acc[2][2];
#pragma unroll
      for (int mt = 0; mt < 2; ++mt)
#pragma unroll
        for (int r = 0; r < 4; ++r) {
          acc[mt][0][r] = pre[mt][0][r];
          acc[mt][1][r] = pre[mt][1][r];
        }
      bf16x8 gb0[2], gb1[2];
      gb0[0] = *(const bf16x8*)(g0p);      gb0[1] = *(const bf16x8*)(g0p + 32);
      gb1[0] = *(const bf16x8*)(g1p);      gb1[1] = *(const bf16x8*)(g1p + 32);
#pragma unroll
      for (int kb = 0; kb < 2; ++kb) {
        bf16x8 a0 = *(const bf16x8*)(&eg[wm * 32 + lr][kb * 32 + lk]);
        bf16x8 a1 = *(const bf16x8*)(&eg[wm * 32 + 16 + lr][kb * 32 + lk]);
        acc[0][0] = __builtin_amdgcn_mfma_f32_16x16x32_bf16(a0, gb0[kb], acc[0][0], 0, 0, 0);
        acc[0][1] = __builtin_amdgcn_mfma_f32_16x16x32_bf16(a0, gb1[kb], acc[0][1], 0, 0, 0);
        acc[1][0] = __builtin_amdgcn_mfma_f32_16x16x32_bf16(a1, gb0[kb], acc[1][0], 0, 0, 0);
        acc[1][1] = __builtin_amdgcn_mfma_f32_16x16x32_bf16(a1, gb1[kb], acc[1][1], 0, 0, 0);
      }
#pragma unroll
      for (int mt = 0; mt < 2; ++mt)
#pragma unroll
        for (int r = 0; r < 4; ++r) {
          t1s[wm * 32 + mt * 16 + rr + r][col0] = (__bf16)silu_f(acc[mt][0][r]);
          t1s[wm * 32 + mt * 16 + rr + r][col1] = (__bf16)silu_f(acc[mt][1][r]);
        }
    }
    __syncthreads();   // bar1: eg(t) reads done; t1 visible in t1s

    // Phase B: stage next tile (srcs/dsts/eg); GEMM2 reads t1s -> regs
    if (has_next) {
      const int gi = (tile0 + t + 1) * 64;
      const int s = sp[gi + m], d = dp[gi + m];
      if (p == 3) srcs[nxt][m] = s;
      if (p == 4) dsts[nxt][m] = d;
      if (p < 3) {
        float dd = fc[d * 3 + p] - fc[s * 3 + p];
        dd -= floorf(dd);
        float s1, c1;
        __sincosf(dd * 6.2831853071795864769f, &s1, &c1);
        eg[m][p * 10]      = (__bf16)0.0f;
        eg[m][30 + p * 10] = (__bf16)1.0f;
        float sk = s1, ck = c1;
#pragma unroll
        for (int k = 1; k < 10; ++k) {
          eg[m][p * 10 + k]      = (__bf16)sk;
          eg[m][30 + p * 10 + k] = (__bf16)ck;
          const float sn = sk * c1 + ck * s1, cn = ck * c1 - sk * s1;
          sk = sn; ck = cn;
        }
      }
    }
    f32x4 acc2[2][2] = {};
#pragma unroll
    for (int kb = 0; kb < 4; ++kb) {
      bf16x8 a0 = *(const bf16x8*)(&t1s[wm * 32 + lr][kb * 32 + lk]);
      bf16x8 a1 = *(const bf16x8*)(&t1s[wm * 32 + 16 + lr][kb * 32 + lk]);
      bf16x8 b0 = *(const bf16x8*)(w2p0 + kb * 32);
      bf16x8 b1 = *(const bf16x8*)(w2p1 + kb * 32);
      acc2[0][0] = __builtin_amdgcn_mfma_f32_16x16x32_bf16(a0, b0, acc2[0][0], 0, 0, 0);
      acc2[0][1] = __builtin_amdgcn_mfma_f32_16x16x32_bf16(a0, b1, acc2[0][1], 0, 0, 0);
      acc2[1][0] = __builtin_amdgcn_mfma_f32_16x16x32_bf16(a1, b0, acc2[1][0], 0, 0, 0);
      acc2[1][1] = __builtin_amdgcn_mfma_f32_16x16x32_bf16(a1, b1, acc2[1][1], 0, 0, 0);
    }
    __syncthreads();   // bar2: t1s reads done; srcs/dsts[nxt] visible

    // Phase C': prefetch next tile's gathers (covered by C'+bar3+D+bar4), then ef -> t1s
    if (has_next) PREFETCH(nxt);
#pragma unroll
    for (int mt = 0; mt < 2; ++mt)
#pragma unroll
      for (int r = 0; r < 4; ++r) {
        t1s[wm * 32 + mt * 16 + rr + r][col0] = (__bf16)silu_f(acc2[mt][0][r] + bias2_0);
        t1s[wm * 32 + mt * 16 + rr + r][col1] = (__bf16)silu_f(acc2[mt][1][r] + bias2_1);
      }
    __syncthreads();   // bar3: ef visible

    // Phase D: segmented reduction (4 segments of 16 rows, 128 cols)
    {
      const int col = tid & 127, seg = tid >> 7, r0 = seg * 16;
      const int* sr = srcs[cur];
      int curS = sr[r0];
      float a = 0.f;
#pragma unroll 4
      for (int r = 0; r < 16; ++r) {
        const int s = sr[r0 + r];
        if (s != curS) {
          unsafeAtomicAdd(&agg[(size_t)curS * HH + col], a);
          curS = s; a = 0.f;
        }
        a += (float)t1s[r0 + r][col];
      }
      unsafeAtomicAdd(&agg[(size_t)curS * HH + col], a);
    }
    __syncthreads();   // bar4: t1s free for next tile's Phase A
  }
#undef PREFETCH
}

// ---------------------------------------------------------------------------
// Node MLP via MFMA (8 waves, 16 cols/wave) + fused next-layer Ps/Pd
// ---------------------------------------------------------------------------
__global__ __launch_bounds__(512) void k_node(
    float* __restrict__ h, float* __restrict__ agg, const int* __restrict__ cnt,
    const u16* __restrict__ nwt1, const float* __restrict__ nb1,
    const u16* __restrict__ nwt2, const float* __restrict__ nb2,
    const float* __restrict__ cl, const int* __restrict__ n2g,
    u16* __restrict__ hbf,
    const u16* __restrict__ wt1s, const u16* __restrict__ wt1d,
    const float* __restrict__ Gl,
    float* __restrict__ Ps, float* __restrict__ Pd) {
  __shared__ __align__(16) __bf16 einp[32][264];
  __shared__ __align__(16) __bf16 t1n[32][136];
  const int tid = threadIdx.x, lane = tid & 63, w = tid >> 6;   // 8 waves
  const int lr = lane & 15, lk = (lane >> 4) * 8, rr = (lane >> 4) * 4;
  const int m = tid >> 4, p = tid & 15;    // staging: 16 threads per node
  const int n0 = blockIdx.x * 32;
  const int col = w * 16 + lr;             // each wave owns 16 cols
  {
    const int n = n0 + m;
    const uint4* hr = (const uint4*)(hbf + (size_t)n * 128);
    *(uint4*)(&einp[m][p * 8]) = hr[p];
    const float inv = 1.f / fmaxf((float)cnt[n], 1.f);
    const float4* ar = (const float4*)(agg + (size_t)n * 128);
    union { __bf16 b[8]; uint4 u; } tmp;
#pragma unroll
    for (int q = 0; q < 2; ++q) {
      const float4 v = ar[p * 2 + q];
      tmp.b[q * 4 + 0] = (__bf16)(v.x * inv);
      tmp.b[q * 4 + 1] = (__bf16)(v.y * inv);
      tmp.b[q * 4 + 2] = (__bf16)(v.z * inv);
      tmp.b[q * 4 + 3] = (__bf16)(v.w * inv);
    }
    *(uint4*)(&einp[m][128 + p * 8]) = tmp.u;
  }
  __syncthreads();
  f32x4 acc[2] = {};
  {
    const u16* w0 = nwt1 + (size_t)col * 256 + lk;
#pragma unroll
    for (int kb = 0; kb < 8; ++kb) {
      bf16x8 a0 = *(const bf16x8*)(&einp[lr][kb * 32 + lk]);
      bf16x8 a1 = *(const bf16x8*)(&einp[16 + lr][kb * 32 + lk]);
      bf16x8 b0 = *(const bf16x8*)(w0 + kb * 32);
      acc[0] = __builtin_amdgcn_mfma_f32_16x16x32_bf16(a0, b0, acc[0], 0, 0, 0);
      acc[1] = __builtin_amdgcn_mfma_f32_16x16x32_bf16(a1, b0, acc[1], 0, 0, 0);
    }
  }
  {
    const float bias = nb1[col];
#pragma unroll
    for (int mt = 0; mt < 2; ++mt)
#pragma unroll
      for (int r = 0; r < 4; ++r)
        t1n[mt * 16 + rr + r][col] = (__bf16)silu_f(acc[mt][r] + bias);
  }
  __syncthreads();
  f32x4 acc2[2] = {};
  {
    const u16* w0 = nwt2 + (size_t)col * 128 + lk;
#pragma unroll
    for (int kb = 0; kb < 4; ++kb) {
      bf16x8 a0 = *(const bf16x8*)(&t1n[lr][kb * 32 + lk]);
      bf16x8 a1 = *(const bf16x8*)(&t1n[16 + lr][kb * 32 + lk]);
      bf16x8 b0 = *(const bf16x8*)(w0 + kb * 32);
      acc2[0] = __builtin_amdgcn_mfma_f32_16x16x32_bf16(a0, b0, acc2[0], 0, 0, 0);
      acc2[1] = __builtin_amdgcn_mfma_f32_16x16x32_bf16(a1, b0, acc2[1], 0, 0, 0);
    }
  }
  __syncthreads();   // t1n reads done; safe to overwrite with new hbf
  {
    const float bias = nb2[col];
#pragma unroll
    for (int mt = 0; mt < 2; ++mt)
#pragma unroll
      for (int r = 0; r < 4; ++r) {
        const int row = mt * 16 + rr + r;
        const int n = n0 + row;
        const float rv = h[(size_t)n * 128 + col] + silu_f(acc2[mt][r] + bias)
                       + cl[(size_t)n2g[n] * 128 + col];
        h[(size_t)n * 128 + col] = rv;
        const u16 bf = f2bf(rv);
        hbf[(size_t)n * 128 + col] = bf;
        t1n[row][col] = *(const __bf16*)&bf;
        agg[(size_t)n * 128 + col] = 0.f;
      }
  }
  if (!wt1s) return;
  __syncthreads();   // new hbf in t1n ready
  f32x4 as[2] = {}, ad[2] = {};
  {
    const u16* ws0 = wt1s + (size_t)col * 128 + lk;
    const u16* wd0 = wt1d + (size_t)col * 128 + lk;
#pragma unroll
    for (int kb = 0; kb < 4; ++kb) {
      bf16x8 a0 = *(const bf16x8*)(&t1n[lr][kb * 32 + lk]);
      bf16x8 a1 = *(const bf16x8*)(&t1n[16 + lr][kb * 32 + lk]);
      bf16x8 bs0 = *(const bf16x8*)(ws0 + kb * 32);
      bf16x8 bd0 = *(const bf16x8*)(wd0 + kb * 32);
      as[0] = __builtin_amdgcn_mfma_f32_16x16x32_bf16(a0, bs0, as[0], 0, 0, 0);
      as[1] = __builtin_amdgcn_mfma_f32_16x16x32_bf16(a1, bs0, as[1], 0, 0, 0);
      ad[0] = __builtin_amdgcn_mfma_f32_16x16x32_bf16(a0, bd0, ad[0], 0, 0, 0);
      ad[1] = __builtin_amdgcn_mfma_f32_16x16x32_bf16(a1, bd0, ad[1], 0, 0, 0);
    }
  }
#pragma unroll
  for (int mt = 0; mt < 2; ++mt)
#pragma unroll
    for (int r = 0; r < 4; ++r) {
      const int n = n0 + mt * 16 + rr + r;
      Ps[(size_t)n * 128 + col] = as[mt][r] + Gl[(size_t)n2g[n] * 128 + col];
      Pd[(size_t)n * 128 + col] = ad[mt][r];
    }
}

// ---------------------------------------------------------------------------
// Output heads (coord + lattice fused)
// ---------------------------------------------------------------------------
__global__ __launch_bounds__(256) void k_heads(
    const float* __restrict__ h, const float* __restrict__ Wc,
    const float* __restrict__ Wl9, const float* __restrict__ lat,
    float* __restrict__ out) {
  const int b = blockIdx.x, tid = threadIdx.x;
  if (b < NN * 3 / 256) {
    const int idx = b * 256 + tid;
    const int n = idx / 3, j = idx % 3;
    float s = 0.f;
    for (int k = 0; k < 128; ++k) s += h[n * 128 + k] * Wc[k * 3 + j];
    out[BB * 9 + idx] = s;
    return;
  }
  const int g = b - NN * 3 / 256;
  __shared__ float part[2][128];
  __shared__ float gf[128];
  __shared__ float lo[9];
  const int c = tid & 127, half = tid >> 7;
  float s = 0.f;
  for (int mm = 0; mm < 16; ++mm)
    s += h[((size_t)g * 32 + half * 16 + mm) * 128 + c];
  part[half][c] = s;
  __syncthreads();
  if (tid < 128) gf[tid] = (part[0][tid] + part[1][tid]) * (1.f / 32.f);
  __syncthreads();
  if (tid < 9) {
    float t = 0.f;
    for (int k = 0; k < 128; ++k) t += gf[k] * Wl9[k * 9 + tid];
    lo[tid] = t;
  }
  __syncthreads();
  if (tid < 9) {
    const int i = tid / 3, kk = tid % 3;
    float t = 0.f;
#pragma unroll
    for (int j = 0; j < 3; ++j) t += lo[i * 3 + j] * lat[g * 9 + j * 3 + kk];
    out[g * 9 + tid] = t;
  }
}

// ---------------------------------------------------------------------------
extern "C" void kernel_launch(void* const* d_in, const int* in_sizes, int n_in,
                              void* d_out, int out_size, void* d_ws, size_t ws_size,
                              hipStream_t stream) {
  const int*   atom_types = (const int*)  d_in[0];
  const float* frac       = (const float*)d_in[1];
  const float* lattices   = (const float*)d_in[2];
  const float* z          = (const float*)d_in[3];
  const float* cemb       = (const float*)d_in[4];
  const int*   ei         = (const int*)  d_in[5];
  const int*   n2g        = (const int*)  d_in[6];
  const float* emb        = (const float*)d_in[7];
  const float* W_lat      = (const float*)d_in[8];
  const float* b_lat      = (const float*)d_in[9];
  const float* ew1        = (const float*)d_in[10];
  const float* eb1        = (const float*)d_in[11];
  const float* ew2        = (const float*)d_in[12];
  const float* eb2        = (const float*)d_in[13];
  const float* nw1        = (const float*)d_in[14];
  const float* nb1        = (const float*)d_in[15];
  const float* nw2        = (const float*)d_in[16];
  const float* nb2        = (const float*)d_in[17];
  const float* mixin      = (const float*)d_in[18];
  const float* aw1        = (const float*)d_in[19];
  const float* ab1        = (const float*)d_in[20];
  const float* aw2        = (const float*)d_in[21];
  const float* ab2        = (const float*)d_in[22];
  const float* Wc         = (const float*)d_in[23];
  const float* Wl9        = (const float*)d_in[24];
  float* out = (float*)d_out;

  uint8_t* base = (uint8_t*)d_ws;
  size_t off = 0;
  auto carve = [&](size_t bytes) -> void* {
    void* r = base + off;
    off = (off + bytes + 255) & ~(size_t)255;
    return r;
  };
  float* h      = (float*)carve((size_t)NN * HH * 4);
  u16*   hbf    = (u16*)  carve((size_t)NN * HH * 2);
  float* agg    = (float*)carve((size_t)NN * HH * 4);
  float* Ps     = (float*)carve((size_t)NN * HH * 4);
  float* Pd     = (float*)carve((size_t)NN * HH * 4);
  float* Gl     = (float*)carve((size_t)LL * BB * HH * 4);
  int*   cnt    = (int*)  carve((size_t)NN * 4);
  int*   cursor = (int*)  carve((size_t)NN * 4);
  int*   sp     = (int*)  carve((size_t)EE * 4);
  int*   dp     = (int*)  carve((size_t)EE * 4);
  float* call   = (float*)carve((size_t)LL * BB * HH * 4);
  u16*   wt1s   = (u16*)  carve((size_t)R_WT1S * 2);
  u16*   wt1d   = (u16*)  carve((size_t)R_WT1D * 2);
  u16*   wt1g   = (u16*)  carve((size_t)R_WT1G * 2);
  u16*   wt2    = (u16*)  carve((size_t)R_WT2 * 2);
  u16*   nwt1   = (u16*)  carve((size_t)R_NWT1 * 2);
  u16*   nwt2   = (u16*)  carve((size_t)R_NWT2 * 2);
  u16*   hwt    = (u16*)  carve((size_t)R_HWT * 2);
  u16*   embbf  = (u16*)  carve((size_t)R_EMB * 2);
  u16*   zbf    = (u16*)  carve((size_t)R_Z * 2);

  hipMemsetAsync(cnt, 0, (size_t)NN * 4, stream);
  k_hist<<<EE / 256, 256, 0, stream>>>(ei, cnt);
  k_scan<<<1, 1024, 0, stream>>>(cnt, cursor);
  k_scatter<<<EE / 256, 256, 0, stream>>>(ei, cursor, sp, dp);
  k_prep<<<(PREP_TOT + 255) / 256, 256, 0, stream>>>(
      ew1, ew2, nw1, nw2, W_lat, emb, z, eb1, lattices,
      wt1s, wt1d, wt1g, wt2, nwt1, nwt2, hwt, embbf, zbf, Gl);
  k_adapt<<<LL * BB, 128, 0, stream>>>(cemb, aw1, ab1, aw2, ab2, mixin, call);
  k_h0<<<NN / 32, 256, 0, stream>>>(atom_types, n2g, embbf, zbf, hwt, b_lat,
                                    wt1s, wt1d, Gl, h, hbf, Ps, Pd);
  hipMemsetAsync(agg, 0, (size_t)NN * HH * 4, stream);  // layers 1..3 zeroed by k_node

  for (int l = 0; l < LL; ++l) {
    k_edge<<<EE / (64 * TPB), 512, 0, stream>>>(Ps, Pd, frac, sp, dp,
        wt1g + (size_t)l * 128 * 64, wt2 + (size_t)l * 128 * 128,
        eb2 + l * 128, agg);
    const bool more = (l + 1 < LL);
    k_node<<<NN / 32, 512, 0, stream>>>(h, agg, cnt,
        nwt1 + (size_t)l * 128 * 256, nb1 + l * 128,
        nwt2 + (size_t)l * 128 * 128, nb2 + l * 128,
        call + (size_t)l * BB * HH, n2g, hbf,
        more ? wt1s + (size_t)(l + 1) * 128 * 128 : (const u16*)nullptr,
        more ? wt1d + (size_t)(l + 1) * 128 * 128 : (const u16*)nullptr,
        more ? Gl + (size_t)(l + 1) * BB * HH : (const float*)nullptr,
        Ps, Pd);
  }

  k_heads<<<NN * 3 / 256 + BB, 256, 0, stream>>>(h, Wc, Wl9, lattices, out);
}